// Round 2
// baseline (12631.627 us; speedup 1.0000x reference)
//
#include <hip/hip_runtime.h>
#include <hip/hip_bf16.h>
#include <stdint.h>

#define NN 50000
#define EE 800000

typedef unsigned short u16;

__device__ __forceinline__ float bu2f(u16 u){ return __uint_as_float(((unsigned)u)<<16); }
__device__ __forceinline__ u16 f2bu(float f){
  unsigned u = __float_as_uint(f);
  u += 0x7fffu + ((u>>16)&1u);      // round-to-nearest-even
  return (u16)(u>>16);
}

// ---------- sniff: flags[0] = edges are int64; flags[1] = float inputs are bf16 ----------
__global__ void sniff_kernel(const int* __restrict__ e, const u16* __restrict__ xu,
                             int* __restrict__ flags){
  __shared__ int nz, cnt;
  int t = threadIdx.x;
  if (t == 0){ nz = 0; cnt = 0; }
  __syncthreads();
  // int64 edges (values < 50000) => every odd 32-bit word is 0
  if (e[2*t + 1] != 0) atomicOr(&nz, 1);
  // bf16 x => even halfwords are valid bf16 of N(0,1): exponent field in [118,132]
  // f32 x  => even halfwords are low mantissa bits: ~uniform, ~6% land in window
  u16 u = xu[2*t];
  int ef = (u >> 7) & 0xFF;
  int ok = (u == 0) || (ef >= 118 && ef <= 132);
  atomicAdd(&cnt, ok);
  __syncthreads();
  if (t == 0){ flags[0] = (nz == 0) ? 1 : 0; flags[1] = (cnt >= 200) ? 1 : 0; }
}

__global__ void convert_edges_kernel(const void* __restrict__ ep, int* __restrict__ outp,
                                     const int* __restrict__ flags, int total){
  int i = blockIdx.x*256 + threadIdx.x;
  if (i >= total) return;
  if (flags[0]) outp[i] = (int)((const long long*)ep)[i];
  else          outp[i] = ((const int*)ep)[i];
}

// ---------- canonicalize 15 float param arrays to fp32 in ws ----------
struct ParamTab {
  const void* src[15];
  float*      dst[15];
  int         sz[15];
};

__global__ __launch_bounds__(256) void canon_params_kernel(ParamTab tab, const int* __restrict__ flags){
  int a = blockIdx.x;
  int isbf = flags[1];
  const void* s = tab.src[a];
  float* d = tab.dst[a];
  int n = tab.sz[a];
  for (int i = threadIdx.x; i < n; i += 256)
    d[i] = isbf ? bu2f(((const u16*)s)[i]) : ((const float*)s)[i];
}

// ---------- conv3x3 VALID + bias + concat(bd) + relu -> h0 [NN][656] (cols 652..655 zero) ----------
__global__ __launch_bounds__(256) void conv_relu_kernel(
    const void* __restrict__ xraw, const void* __restrict__ bdraw,
    const float* __restrict__ cw, const float* __restrict__ cb,
    const int* __restrict__ flags, float* __restrict__ h0){
  __shared__ float xs[968];    // 8*121
  __shared__ float wsm[576];   // 8*8*9
  __shared__ float bs[8];
  int n = blockIdx.x, t = threadIdx.x;
  int isbf = flags[1];
  if (isbf){
    const ushort4* xp = (const ushort4*)((const u16*)xraw + (size_t)n*968);
    if (t < 242){ ushort4 u = xp[t]; xs[4*t]=bu2f(u.x); xs[4*t+1]=bu2f(u.y); xs[4*t+2]=bu2f(u.z); xs[4*t+3]=bu2f(u.w); }
  } else {
    const float4* xp = (const float4*)((const float*)xraw + (size_t)n*968);
    if (t < 242){ float4 u = xp[t]; xs[4*t]=u.x; xs[4*t+1]=u.y; xs[4*t+2]=u.z; xs[4*t+3]=u.w; }
  }
  if (t < 144){ float4 u = ((const float4*)cw)[t]; wsm[4*t]=u.x; wsm[4*t+1]=u.y; wsm[4*t+2]=u.z; wsm[4*t+3]=u.w; }
  if (t < 8) bs[t] = cb[t];
  __syncthreads();
  float* outr = h0 + (size_t)n*656;
  for (int idx = t; idx < 656; idx += 256){
    float v;
    if (idx < 648){
      int co = idx/81, rem = idx%81, oi = rem/9, oj = rem%9;
      float acc = bs[co];
      const float* wp = wsm + co*72;
      const float* xb = xs + oi*11 + oj;
      #pragma unroll
      for (int ci=0; ci<8; ci++)
        #pragma unroll
        for (int ki=0; ki<3; ki++)
          #pragma unroll
          for (int kj=0; kj<3; kj++)
            acc += xb[ci*121 + ki*11 + kj] * wp[ci*9 + ki*3 + kj];
      v = acc;
    } else if (idx < 652){
      int j = idx - 648;
      v = isbf ? bu2f(((const u16*)bdraw)[(size_t)n*4 + j]) : ((const float*)bdraw)[(size_t)n*4 + j];
    } else {
      v = 0.f;  // zero pad so GEMM can read K-tiles without guards
    }
    outr[idx] = fmaxf(v, 0.f);
  }
}

// ---------- degree ----------
__global__ void deg_kernel(const int* __restrict__ dst, int* __restrict__ degI, int E){
  int e = blockIdx.x*256 + threadIdx.x;
  if (e < E) atomicAdd(&degI[dst[e]], 1);
}
__global__ void invdeg_kernel(const int* __restrict__ degI, float* __restrict__ inv, int n){
  int i = blockIdx.x*256 + threadIdx.x;
  if (i < n){ int d = degI[i]; inv[i] = 1.0f / (float)(d > 1 ? d : 1); }
}

// ---------- scatter add: dst_feat[edst[e]] += src_feat[esrc[e]]  (1 wave / edge) ----------
__global__ __launch_bounds__(256) void scatter_add_kernel(
    const float* __restrict__ src_feat, float* __restrict__ dst_feat,
    const int* __restrict__ esrc, const int* __restrict__ edst, int E){
  int wid = threadIdx.x >> 6, lane = threadIdx.x & 63;
  int e = blockIdx.x*4 + wid;
  if (e >= E) return;
  int s = esrc[e], d = edst[e];
  float4 v = *(const float4*)(src_feat + (size_t)s*256 + lane*4);
  float* dp = dst_feat + (size_t)d*256 + lane*4;
  unsafeAtomicAdd(dp+0, v.x);
  unsafeAtomicAdd(dp+1, v.y);
  unsafeAtomicAdd(dp+2, v.z);
  unsafeAtomicAdd(dp+3, v.w);
}

// ---------- fused GEMM: out = scale[m]*(A1 @ W1^T) + (A2 @ W2^T) + bias ----------
// A fp32 [M][lda], W fp32 [256][K] row-major (canon). N fixed = 256, tile 64x64, BK=16.
__global__ __launch_bounds__(256) void gemm_fused_kernel(
    const float* __restrict__ A1, int lda1,
    const float* __restrict__ W1, int K1,
    const float* __restrict__ scale,
    const float* __restrict__ A2, int lda2,
    const float* __restrict__ W2, int K2,
    const float* __restrict__ bias,
    float* __restrict__ out_f32,
    void* __restrict__ out_emb,
    float* __restrict__ out_relu,
    const int* __restrict__ flags,
    int M){
  __shared__ float As[16][68];
  __shared__ float Bs[16][68];
  int t = threadIdx.x;
  int m0 = blockIdx.x << 6;
  int o0 = blockIdx.y << 6;
  int rm = (t >> 4) << 2;   // row offset in tile, 0..60
  int cn = (t & 15) << 2;   // col offset in tile, 0..60
  int lr = t >> 2;          // loader row 0..63
  int lk = (t & 3) << 2;    // loader k 0,4,8,12
  float acc[4][4] = {{0.f}};

  for (int pass = 0; pass < 2; ++pass){
    const float* A; const float* W; int K, lda;
    if (pass == 0){ A = A1; W = W1; K = K1; lda = lda1; }
    else { if (!A2) break; A = A2; W = W2; K = K2; lda = lda2; }
    int ntile = (K + 15) >> 4;
    for (int kt = 0; kt < ntile; ++kt){
      int k0 = kt << 4;
      int gm = m0 + lr;
      float4 a = make_float4(0.f,0.f,0.f,0.f);
      if (gm < M) a = *(const float4*)(A + (size_t)gm*lda + (k0 + lk));  // lda padded => no k guard
      As[lk+0][lr]=a.x; As[lk+1][lr]=a.y; As[lk+2][lr]=a.z; As[lk+3][lr]=a.w;
      int go = o0 + lr;           // always < 256
      int kg = k0 + lk;
      const float* wp = W + (size_t)go*K + kg;
      float4 wv;
      if (kg + 3 < K){
        wv = *(const float4*)wp;   // 16B-aligned (K%4==0, kg%4==0)
      } else {
        wv.x = (kg+0 < K) ? wp[0] : 0.f;
        wv.y = (kg+1 < K) ? wp[1] : 0.f;
        wv.z = (kg+2 < K) ? wp[2] : 0.f;
        wv.w = (kg+3 < K) ? wp[3] : 0.f;
      }
      Bs[lk+0][lr]=wv.x; Bs[lk+1][lr]=wv.y; Bs[lk+2][lr]=wv.z; Bs[lk+3][lr]=wv.w;
      __syncthreads();
      #pragma unroll
      for (int k = 0; k < 16; k++){
        float4 av = *(const float4*)&As[k][rm];
        float4 bv = *(const float4*)&Bs[k][cn];
        float aa[4] = {av.x, av.y, av.z, av.w};
        float bb[4] = {bv.x, bv.y, bv.z, bv.w};
        #pragma unroll
        for (int i = 0; i < 4; i++)
          #pragma unroll
          for (int j = 0; j < 4; j++)
            acc[i][j] += aa[i]*bb[j];
      }
      __syncthreads();
    }
    if (pass == 0 && scale){
      #pragma unroll
      for (int i = 0; i < 4; i++){
        int gm = m0 + rm + i;
        float s = (gm < M) ? scale[gm] : 0.f;
        #pragma unroll
        for (int j = 0; j < 4; j++) acc[i][j] *= s;
      }
    }
  }
  int isbf = flags[1];
  float bv[4];
  #pragma unroll
  for (int j = 0; j < 4; j++) bv[j] = bias[o0 + cn + j];
  #pragma unroll
  for (int i = 0; i < 4; i++){
    int gm = m0 + rm + i;
    if (gm < M){
      size_t ro = (size_t)gm*256 + o0 + cn;
      #pragma unroll
      for (int j = 0; j < 4; j++){
        float v = acc[i][j] + bv[j];
        if (out_f32)  out_f32[ro+j]  = v;
        if (out_emb){
          if (isbf) ((u16*)out_emb)[ro+j] = f2bu(v);
          else      ((float*)out_emb)[ro+j] = v;
        }
        if (out_relu) out_relu[ro+j] = fmaxf(v, 0.f);
      }
    }
  }
}

// ---------- relu + layernorm (block per node, 256 threads = 256 features) ----------
__global__ __launch_bounds__(256) void relu_ln_kernel(
    const float* __restrict__ inb, float* __restrict__ outb,
    const float* __restrict__ g, const float* __restrict__ b){
  __shared__ float rs[4], rs2[4];
  int n = blockIdx.x, t = threadIdx.x;
  float v = fmaxf(inb[(size_t)n*256 + t], 0.f);
  float s = v, s2 = v*v;
  #pragma unroll
  for (int off = 1; off < 64; off <<= 1){ s += __shfl_xor(s, off); s2 += __shfl_xor(s2, off); }
  if ((t & 63) == 0){ rs[t>>6] = s; rs2[t>>6] = s2; }
  __syncthreads();
  float S  = rs[0]+rs[1]+rs[2]+rs[3];
  float S2 = rs2[0]+rs2[1]+rs2[2]+rs2[3];
  float mu  = S * (1.f/256.f);
  float var = S2 * (1.f/256.f) - mu*mu;
  float inv = rsqrtf(var + 1e-5f);
  outb[(size_t)n*256 + t] = (v - mu) * inv * g[t] + b[t];
}

// ---------- head: z2 = z1 @ mp2^T + b2; log_softmax; thread per node ----------
__global__ __launch_bounds__(256) void head_kernel(
    const float* __restrict__ z1, const float* __restrict__ w2, const float* __restrict__ b2,
    void* __restrict__ outbase, size_t out_off, const int* __restrict__ flags, int M){
  __shared__ float wsm[1280];   // 5*256
  __shared__ float bs[5];
  int t = threadIdx.x;
  for (int i = t; i < 320; i += 256){
    float4 u = ((const float4*)w2)[i];
    wsm[4*i]=u.x; wsm[4*i+1]=u.y; wsm[4*i+2]=u.z; wsm[4*i+3]=u.w;
  }
  if (t < 5) bs[t] = b2[t];
  __syncthreads();
  int n = blockIdx.x*256 + t;
  if (n >= M) return;
  const float* zp = z1 + (size_t)n*256;
  float acc[5];
  #pragma unroll
  for (int o = 0; o < 5; o++) acc[o] = bs[o];
  for (int k = 0; k < 256; k += 4){
    float4 z = *(const float4*)(zp + k);
    #pragma unroll
    for (int o = 0; o < 5; o++){
      const float* w = wsm + o*256 + k;
      acc[o] += z.x*w[0] + z.y*w[1] + z.z*w[2] + z.w*w[3];
    }
  }
  float mx = acc[0];
  #pragma unroll
  for (int o = 1; o < 5; o++) mx = fmaxf(mx, acc[o]);
  float se = 0.f;
  #pragma unroll
  for (int o = 0; o < 5; o++) se += expf(acc[o] - mx);
  float lse = mx + logf(se);
  int isbf = flags[1];
  if (isbf){
    u16* op = (u16*)outbase + out_off + (size_t)n*5;
    #pragma unroll
    for (int o = 0; o < 5; o++) op[o] = f2bu(acc[o] - lse);
  } else {
    float* op = (float*)outbase + out_off + (size_t)n*5;
    #pragma unroll
    for (int o = 0; o < 5; o++) op[o] = acc[o] - lse;
  }
}

extern "C" void kernel_launch(void* const* d_in, const int* in_sizes, int n_in,
                              void* d_out, int out_size, void* d_ws, size_t ws_size,
                              hipStream_t stream){
  (void)in_sizes; (void)n_in; (void)out_size; (void)ws_size;
  const void* x    = d_in[0];
  const void* bd   = d_in[1];
  const void* eraw = d_in[2];

  char* ws = (char*)d_ws;
  const size_t OFF_H0 = 0;
  const size_t OFF_A  = OFF_H0 + (size_t)NN*656*4;
  const size_t OFF_B  = OFF_A  + (size_t)NN*256*4;
  const size_t OFF_C  = OFF_B  + (size_t)NN*256*4;
  const size_t OFF_DEG= OFF_C  + (size_t)NN*256*4;
  const size_t OFF_INV= OFF_DEG + (size_t)NN*4;
  const size_t OFF_EDG= OFF_INV + (size_t)NN*4;
  const size_t OFF_FLG= OFF_EDG + (size_t)2*EE*4;
  const size_t OFF_PRM= OFF_FLG + 256;   // canon fp32 params

  float* h0   = (float*)(ws + OFF_H0);
  float* bufA = (float*)(ws + OFF_A);
  float* bufB = (float*)(ws + OFF_B);
  float* bufC = (float*)(ws + OFF_C);
  int*   degI = (int*)(ws + OFF_DEG);
  float* invd = (float*)(ws + OFF_INV);
  int*   edg  = (int*)(ws + OFF_EDG);
  int*   flg  = (int*)(ws + OFF_FLG);
  float* prm  = (float*)(ws + OFF_PRM);
  const int* esrc = edg;
  const int* edst = edg + EE;

  // canon param layout (fp32, offsets in elements, padded to 16)
  static const int psz[15] = {576, 8, 166912, 256, 166912, 256, 196608, 768, 196608, 512, 512, 65536, 256, 1280, 16};
  size_t poff[15]; size_t acc_off = 0;
  for (int i = 0; i < 15; i++){ poff[i] = acc_off; acc_off += (size_t)((psz[i] + 15) & ~15); }
  ParamTab tab;
  for (int i = 0; i < 15; i++){ tab.src[i] = d_in[3 + i]; tab.dst[i] = prm + poff[i]; tab.sz[i] = psz[i]; }
  tab.sz[14] = 5;  // mp2_b true size
  const float* c_cw   = prm + poff[0];
  const float* c_cb   = prm + poff[1];
  const float* c_lw   = prm + poff[2];
  const float* c_lb   = prm + poff[3];
  const float* c_lsw  = prm + poff[4];
  const float* c_lsb  = prm + poff[5];
  const float* c_slw  = prm + poff[6];
  const float* c_slb  = prm + poff[7];
  const float* c_srw  = prm + poff[8];
  const float* c_lng  = prm + poff[9];
  const float* c_lnb  = prm + poff[10];
  const float* c_m1w  = prm + poff[11];
  const float* c_m1b  = prm + poff[12];
  const float* c_m2w  = prm + poff[13];
  const float* c_m2b  = prm + poff[14];

  hipMemsetAsync(degI, 0, (size_t)NN*4, stream);
  sniff_kernel<<<1, 256, 0, stream>>>((const int*)eraw, (const u16*)x, flg);
  canon_params_kernel<<<15, 256, 0, stream>>>(tab, flg);
  convert_edges_kernel<<<(2*EE + 255)/256, 256, 0, stream>>>(eraw, edg, flg, 2*EE);
  conv_relu_kernel<<<NN, 256, 0, stream>>>(x, bd, c_cw, c_cb, flg, h0);
  deg_kernel<<<(EE + 255)/256, 256, 0, stream>>>(edst, degI, EE);
  invdeg_kernel<<<(NN + 255)/256, 256, 0, stream>>>(degI, invd, NN);

  dim3 ggrid((NN + 63)/64, 4);
  // layer 0: self_x -> bufA, neigh -> bufB, then h = self_x + scatter(neigh)
  gemm_fused_kernel<<<ggrid, 256, 0, stream>>>(h0, 656, c_lsw, 652,
      nullptr, nullptr, 0, nullptr, 0, c_lsb, bufA, nullptr, nullptr, flg, NN);
  gemm_fused_kernel<<<ggrid, 256, 0, stream>>>(h0, 656, c_lw, 652,
      nullptr, nullptr, 0, nullptr, 0, c_lb, bufB, nullptr, nullptr, flg, NN);
  scatter_add_kernel<<<(EE + 3)/4, 256, 0, stream>>>(bufB, bufA, esrc, edst, EE);

  // SAGE layers: h in bufA; mean-sum in bufC; gemm2 -> bufB
  for (int i = 0; i < 3; i++){
    hipMemsetAsync(bufC, 0, (size_t)NN*256*4, stream);
    scatter_add_kernel<<<(EE + 3)/4, 256, 0, stream>>>(bufA, bufC, esrc, edst, EE);
    const float* L  = c_slw + (size_t)i*256*256;
    const float* Lb = c_slb + (size_t)i*256;
    const float* R  = c_srw + (size_t)i*256*256;
    if (i < 2){
      gemm_fused_kernel<<<ggrid, 256, 0, stream>>>(bufC, 256, L, 256,
          invd, bufA, 256, R, 256, Lb, bufB, nullptr, nullptr, flg, NN);
      relu_ln_kernel<<<NN, 256, 0, stream>>>(bufB, bufA,
          c_lng + (size_t)i*256, c_lnb + (size_t)i*256);
    } else {
      // emb (raw, dtype per flag) -> d_out; relu(h) -> bufB for the MLP head
      gemm_fused_kernel<<<ggrid, 256, 0, stream>>>(bufC, 256, L, 256,
          invd, bufA, 256, R, 256, Lb, nullptr, d_out, bufB, flg, NN);
    }
  }
  // z1 = relu_h @ mp1^T + b -> bufC
  gemm_fused_kernel<<<ggrid, 256, 0, stream>>>(bufB, 256, c_m1w, 256,
      nullptr, nullptr, 0, nullptr, 0, c_m1b, bufC, nullptr, nullptr, flg, NN);
  head_kernel<<<(NN + 255)/256, 256, 0, stream>>>(bufC, c_m2w, c_m2b,
      d_out, (size_t)NN*256, flg, NN);
}

// Round 3
// 2506.504 us; speedup vs baseline: 5.0395x; 5.0395x over previous
//
#include <hip/hip_runtime.h>
#include <hip/hip_bf16.h>
#include <stdint.h>

#define NN 50000
#define EE 800000

typedef unsigned short u16;

__device__ __forceinline__ float bu2f(u16 u){ return __uint_as_float(((unsigned)u)<<16); }
__device__ __forceinline__ u16 f2bu(float f){
  unsigned u = __float_as_uint(f);
  u += 0x7fffu + ((u>>16)&1u);      // round-to-nearest-even
  return (u16)(u>>16);
}

// ---------- sniff: flags[0] = edges are int64; flags[1] = float inputs are bf16 ----------
__global__ void sniff_kernel(const int* __restrict__ e, const u16* __restrict__ xu,
                             int* __restrict__ flags){
  __shared__ int nz, cnt;
  int t = threadIdx.x;
  if (t == 0){ nz = 0; cnt = 0; }
  __syncthreads();
  if (e[2*t + 1] != 0) atomicOr(&nz, 1);
  u16 u = xu[2*t];
  int ef = (u >> 7) & 0xFF;
  int ok = (u == 0) || (ef >= 118 && ef <= 132);
  atomicAdd(&cnt, ok);
  __syncthreads();
  if (t == 0){ flags[0] = (nz == 0) ? 1 : 0; flags[1] = (cnt >= 200) ? 1 : 0; }
}

__global__ void convert_edges_kernel(const void* __restrict__ ep, int* __restrict__ outp,
                                     const int* __restrict__ flags, int total){
  int i = blockIdx.x*256 + threadIdx.x;
  if (i >= total) return;
  if (flags[0]) outp[i] = (int)((const long long*)ep)[i];
  else          outp[i] = ((const int*)ep)[i];
}

// ---------- canonicalize 15 float param arrays to fp32 in ws ----------
struct ParamTab {
  const void* src[15];
  float*      dst[15];
  int         sz[15];
};

__global__ __launch_bounds__(256) void canon_params_kernel(ParamTab tab, const int* __restrict__ flags){
  int a = blockIdx.x;
  int isbf = flags[1];
  const void* s = tab.src[a];
  float* d = tab.dst[a];
  int n = tab.sz[a];
  for (int i = threadIdx.x; i < n; i += 256)
    d[i] = isbf ? bu2f(((const u16*)s)[i]) : ((const float*)s)[i];
}

// ---------- conv3x3 VALID + bias + concat(bd) + relu -> h0 [NN][656] ----------
__global__ __launch_bounds__(256) void conv_relu_kernel(
    const void* __restrict__ xraw, const void* __restrict__ bdraw,
    const float* __restrict__ cw, const float* __restrict__ cb,
    const int* __restrict__ flags, float* __restrict__ h0){
  __shared__ float xs[968];    // 8*121
  __shared__ float wsm[576];   // 8*8*9
  __shared__ float bs[8];
  int n = blockIdx.x, t = threadIdx.x;
  int isbf = flags[1];
  if (isbf){
    const ushort4* xp = (const ushort4*)((const u16*)xraw + (size_t)n*968);
    if (t < 242){ ushort4 u = xp[t]; xs[4*t]=bu2f(u.x); xs[4*t+1]=bu2f(u.y); xs[4*t+2]=bu2f(u.z); xs[4*t+3]=bu2f(u.w); }
  } else {
    const float4* xp = (const float4*)((const float*)xraw + (size_t)n*968);
    if (t < 242){ float4 u = xp[t]; xs[4*t]=u.x; xs[4*t+1]=u.y; xs[4*t+2]=u.z; xs[4*t+3]=u.w; }
  }
  if (t < 144){ float4 u = ((const float4*)cw)[t]; wsm[4*t]=u.x; wsm[4*t+1]=u.y; wsm[4*t+2]=u.z; wsm[4*t+3]=u.w; }
  if (t < 8) bs[t] = cb[t];
  __syncthreads();
  float* outr = h0 + (size_t)n*656;
  for (int idx = t; idx < 656; idx += 256){
    float v;
    if (idx < 648){
      int co = idx/81, rem = idx%81, oi = rem/9, oj = rem%9;
      float acc = bs[co];
      const float* wp = wsm + co*72;
      const float* xb = xs + oi*11 + oj;
      #pragma unroll
      for (int ci=0; ci<8; ci++)
        #pragma unroll
        for (int ki=0; ki<3; ki++)
          #pragma unroll
          for (int kj=0; kj<3; kj++)
            acc += xb[ci*121 + ki*11 + kj] * wp[ci*9 + ki*3 + kj];
      v = acc;
    } else if (idx < 652){
      int j = idx - 648;
      v = isbf ? bu2f(((const u16*)bdraw)[(size_t)n*4 + j]) : ((const float*)bdraw)[(size_t)n*4 + j];
    } else {
      v = 0.f;
    }
    outr[idx] = fmaxf(v, 0.f);
  }
}

// ---------- degree ----------
__global__ void deg_kernel(const int* __restrict__ dst, int* __restrict__ degI, int E){
  int e = blockIdx.x*256 + threadIdx.x;
  if (e < E) atomicAdd(&degI[dst[e]], 1);
}
__global__ void invdeg_kernel(const int* __restrict__ degI, float* __restrict__ inv, int n){
  int i = blockIdx.x*256 + threadIdx.x;
  if (i < n){ int d = degI[i]; inv[i] = 1.0f / (float)(d > 1 ? d : 1); }
}

// ---------- exclusive scan of degI -> rowptr (single block, 1024 threads) ----------
__global__ __launch_bounds__(1024) void scan_kernel(const int* __restrict__ degI,
                                                    int* __restrict__ rowptr,
                                                    int* __restrict__ cursor, int n){
  __shared__ int warp_sums[16];
  __shared__ int carry;
  int t = threadIdx.x;
  if (t == 0) carry = 0;
  __syncthreads();
  for (int base = 0; base < n; base += 1024){
    int i = base + t;
    int v = (i < n) ? degI[i] : 0;
    int s = v;
    #pragma unroll
    for (int off = 1; off < 64; off <<= 1){ int u = __shfl_up(s, off); if ((t & 63) >= off) s += u; }
    if ((t & 63) == 63) warp_sums[t >> 6] = s;
    __syncthreads();
    if (t < 16){
      int wsv = warp_sums[t];
      #pragma unroll
      for (int off = 1; off < 16; off <<= 1){ int u = __shfl_up(wsv, off); if (t >= off) wsv += u; }
      warp_sums[t] = wsv;
    }
    __syncthreads();
    int block_off = (t >= 64) ? warp_sums[(t >> 6) - 1] : 0;
    int excl = carry + block_off + s - v;
    if (i < n){ rowptr[i] = excl; cursor[i] = excl; }
    int total = warp_sums[15];
    __syncthreads();
    if (t == 0) carry += total;
    __syncthreads();
  }
  if (t == 0) rowptr[n] = carry;
}

// ---------- bucket fill: ebuc[cursor[dst]++] = src ----------
__global__ void bucket_kernel(const int* __restrict__ esrc, const int* __restrict__ edst,
                              int* __restrict__ cursor, int* __restrict__ ebuc, int E){
  int e = blockIdx.x*256 + threadIdx.x;
  if (e < E){ int pos = atomicAdd(&cursor[edst[e]], 1); ebuc[pos] = esrc[e]; }
}

// ---------- gather-aggregate: out[n] = (addbase?addbase[n]:0) + scale[n] * sum_{j in CSR(n)} src[ebuc[j]] ----------
// one wave per node, lane owns float4 columns
__global__ __launch_bounds__(256) void gather_agg_kernel(
    const float* __restrict__ src_feat, const float* __restrict__ addbase,
    const float* __restrict__ scale, float* __restrict__ outp,
    const int* __restrict__ rowptr, const int* __restrict__ ebuc){
  int wid = threadIdx.x >> 6, lane = threadIdx.x & 63;
  int n = blockIdx.x*4 + wid;
  if (n >= NN) return;
  int beg = rowptr[n], end = rowptr[n+1];
  float4 a0 = make_float4(0.f,0.f,0.f,0.f);
  float4 a1 = make_float4(0.f,0.f,0.f,0.f);
  int j = beg;
  for (; j + 1 < end; j += 2){
    int s0 = ebuc[j], s1 = ebuc[j+1];
    float4 v0 = *(const float4*)(src_feat + (size_t)s0*256 + lane*4);
    float4 v1 = *(const float4*)(src_feat + (size_t)s1*256 + lane*4);
    a0.x += v0.x; a0.y += v0.y; a0.z += v0.z; a0.w += v0.w;
    a1.x += v1.x; a1.y += v1.y; a1.z += v1.z; a1.w += v1.w;
  }
  if (j < end){
    int s0 = ebuc[j];
    float4 v0 = *(const float4*)(src_feat + (size_t)s0*256 + lane*4);
    a0.x += v0.x; a0.y += v0.y; a0.z += v0.z; a0.w += v0.w;
  }
  float sc = scale ? scale[n] : 1.f;
  float4 o;
  o.x = (a0.x + a1.x) * sc;
  o.y = (a0.y + a1.y) * sc;
  o.z = (a0.z + a1.z) * sc;
  o.w = (a0.w + a1.w) * sc;
  if (addbase){
    float4 b = *(const float4*)(addbase + (size_t)n*256 + lane*4);
    o.x += b.x; o.y += b.y; o.z += b.z; o.w += b.w;
  }
  *(float4*)(outp + (size_t)n*256 + lane*4) = o;
}

// ---------- fused GEMM: out = (A1 @ W1^T) + (A2 @ W2^T) + bias ----------
__global__ __launch_bounds__(256) void gemm_fused_kernel(
    const float* __restrict__ A1, int lda1,
    const float* __restrict__ W1, int K1,
    const float* __restrict__ A2, int lda2,
    const float* __restrict__ W2, int K2,
    const float* __restrict__ bias,
    float* __restrict__ out_f32,
    void* __restrict__ out_emb,
    float* __restrict__ out_relu,
    const int* __restrict__ flags,
    int M){
  __shared__ float As[16][68];
  __shared__ float Bs[16][68];
  int t = threadIdx.x;
  int m0 = blockIdx.x << 6;
  int o0 = blockIdx.y << 6;
  int rm = (t >> 4) << 2;
  int cn = (t & 15) << 2;
  int lr = t >> 2;
  int lk = (t & 3) << 2;
  float acc[4][4] = {{0.f}};

  for (int pass = 0; pass < 2; ++pass){
    const float* A; const float* W; int K, lda;
    if (pass == 0){ A = A1; W = W1; K = K1; lda = lda1; }
    else { if (!A2) break; A = A2; W = W2; K = K2; lda = lda2; }
    int ntile = (K + 15) >> 4;
    for (int kt = 0; kt < ntile; ++kt){
      int k0 = kt << 4;
      int gm = m0 + lr;
      float4 a = make_float4(0.f,0.f,0.f,0.f);
      if (gm < M) a = *(const float4*)(A + (size_t)gm*lda + (k0 + lk));
      As[lk+0][lr]=a.x; As[lk+1][lr]=a.y; As[lk+2][lr]=a.z; As[lk+3][lr]=a.w;
      int go = o0 + lr;
      int kg = k0 + lk;
      const float* wp = W + (size_t)go*K + kg;
      float4 wv;
      if (kg + 3 < K){
        wv = *(const float4*)wp;
      } else {
        wv.x = (kg+0 < K) ? wp[0] : 0.f;
        wv.y = (kg+1 < K) ? wp[1] : 0.f;
        wv.z = (kg+2 < K) ? wp[2] : 0.f;
        wv.w = (kg+3 < K) ? wp[3] : 0.f;
      }
      Bs[lk+0][lr]=wv.x; Bs[lk+1][lr]=wv.y; Bs[lk+2][lr]=wv.z; Bs[lk+3][lr]=wv.w;
      __syncthreads();
      #pragma unroll
      for (int k = 0; k < 16; k++){
        float4 av = *(const float4*)&As[k][rm];
        float4 bv = *(const float4*)&Bs[k][cn];
        float aa[4] = {av.x, av.y, av.z, av.w};
        float bb[4] = {bv.x, bv.y, bv.z, bv.w};
        #pragma unroll
        for (int i = 0; i < 4; i++)
          #pragma unroll
          for (int j = 0; j < 4; j++)
            acc[i][j] += aa[i]*bb[j];
      }
      __syncthreads();
    }
  }
  int isbf = flags[1];
  float bv[4];
  #pragma unroll
  for (int j = 0; j < 4; j++) bv[j] = bias[o0 + cn + j];
  #pragma unroll
  for (int i = 0; i < 4; i++){
    int gm = m0 + rm + i;
    if (gm < M){
      size_t ro = (size_t)gm*256 + o0 + cn;
      #pragma unroll
      for (int j = 0; j < 4; j++){
        float v = acc[i][j] + bv[j];
        if (out_f32)  out_f32[ro+j]  = v;
        if (out_emb){
          if (isbf) ((u16*)out_emb)[ro+j] = f2bu(v);
          else      ((float*)out_emb)[ro+j] = v;
        }
        if (out_relu) out_relu[ro+j] = fmaxf(v, 0.f);
      }
    }
  }
}

// ---------- relu + layernorm ----------
__global__ __launch_bounds__(256) void relu_ln_kernel(
    const float* __restrict__ inb, float* __restrict__ outb,
    const float* __restrict__ g, const float* __restrict__ b){
  __shared__ float rs[4], rs2[4];
  int n = blockIdx.x, t = threadIdx.x;
  float v = fmaxf(inb[(size_t)n*256 + t], 0.f);
  float s = v, s2 = v*v;
  #pragma unroll
  for (int off = 1; off < 64; off <<= 1){ s += __shfl_xor(s, off); s2 += __shfl_xor(s2, off); }
  if ((t & 63) == 0){ rs[t>>6] = s; rs2[t>>6] = s2; }
  __syncthreads();
  float S  = rs[0]+rs[1]+rs[2]+rs[3];
  float S2 = rs2[0]+rs2[1]+rs2[2]+rs2[3];
  float mu  = S * (1.f/256.f);
  float var = S2 * (1.f/256.f) - mu*mu;
  float inv = rsqrtf(var + 1e-5f);
  outb[(size_t)n*256 + t] = (v - mu) * inv * g[t] + b[t];
}

// ---------- head ----------
__global__ __launch_bounds__(256) void head_kernel(
    const float* __restrict__ z1, const float* __restrict__ w2, const float* __restrict__ b2,
    void* __restrict__ outbase, size_t out_off, const int* __restrict__ flags, int M){
  __shared__ float wsm[1280];
  __shared__ float bs[5];
  int t = threadIdx.x;
  for (int i = t; i < 320; i += 256){
    float4 u = ((const float4*)w2)[i];
    wsm[4*i]=u.x; wsm[4*i+1]=u.y; wsm[4*i+2]=u.z; wsm[4*i+3]=u.w;
  }
  if (t < 5) bs[t] = b2[t];
  __syncthreads();
  int n = blockIdx.x*256 + t;
  if (n >= M) return;
  const float* zp = z1 + (size_t)n*256;
  float acc[5];
  #pragma unroll
  for (int o = 0; o < 5; o++) acc[o] = bs[o];
  for (int k = 0; k < 256; k += 4){
    float4 z = *(const float4*)(zp + k);
    #pragma unroll
    for (int o = 0; o < 5; o++){
      const float* w = wsm + o*256 + k;
      acc[o] += z.x*w[0] + z.y*w[1] + z.z*w[2] + z.w*w[3];
    }
  }
  float mx = acc[0];
  #pragma unroll
  for (int o = 1; o < 5; o++) mx = fmaxf(mx, acc[o]);
  float se = 0.f;
  #pragma unroll
  for (int o = 0; o < 5; o++) se += expf(acc[o] - mx);
  float lse = mx + logf(se);
  int isbf = flags[1];
  if (isbf){
    u16* op = (u16*)outbase + out_off + (size_t)n*5;
    #pragma unroll
    for (int o = 0; o < 5; o++) op[o] = f2bu(acc[o] - lse);
  } else {
    float* op = (float*)outbase + out_off + (size_t)n*5;
    #pragma unroll
    for (int o = 0; o < 5; o++) op[o] = acc[o] - lse;
  }
}

extern "C" void kernel_launch(void* const* d_in, const int* in_sizes, int n_in,
                              void* d_out, int out_size, void* d_ws, size_t ws_size,
                              hipStream_t stream){
  (void)in_sizes; (void)n_in; (void)out_size; (void)ws_size;
  const void* x    = d_in[0];
  const void* bd   = d_in[1];
  const void* eraw = d_in[2];

  char* ws = (char*)d_ws;
  const size_t OFF_H0 = 0;
  const size_t OFF_A  = OFF_H0 + (size_t)NN*656*4;
  const size_t OFF_B  = OFF_A  + (size_t)NN*256*4;
  const size_t OFF_C  = OFF_B  + (size_t)NN*256*4;
  const size_t OFF_DEG= OFF_C  + (size_t)NN*256*4;
  const size_t OFF_INV= OFF_DEG + (size_t)NN*4;
  const size_t OFF_EDG= OFF_INV + (size_t)NN*4;
  const size_t OFF_RP = OFF_EDG + (size_t)2*EE*4;
  const size_t OFF_CUR= OFF_RP  + (size_t)(NN+16)*4;
  const size_t OFF_EBU= OFF_CUR + (size_t)NN*4;
  const size_t OFF_FLG= OFF_EBU + (size_t)EE*4;
  const size_t OFF_PRM= OFF_FLG + 256;

  float* h0   = (float*)(ws + OFF_H0);
  float* bufA = (float*)(ws + OFF_A);
  float* bufB = (float*)(ws + OFF_B);
  float* bufC = (float*)(ws + OFF_C);
  int*   degI = (int*)(ws + OFF_DEG);
  float* invd = (float*)(ws + OFF_INV);
  int*   edg  = (int*)(ws + OFF_EDG);
  int*   rowp = (int*)(ws + OFF_RP);
  int*   curs = (int*)(ws + OFF_CUR);
  int*   ebuc = (int*)(ws + OFF_EBU);
  int*   flg  = (int*)(ws + OFF_FLG);
  float* prm  = (float*)(ws + OFF_PRM);
  const int* esrc = edg;
  const int* edst = edg + EE;

  static const int psz[15] = {576, 8, 166912, 256, 166912, 256, 196608, 768, 196608, 512, 512, 65536, 256, 1280, 16};
  size_t poff[15]; size_t acc_off = 0;
  for (int i = 0; i < 15; i++){ poff[i] = acc_off; acc_off += (size_t)((psz[i] + 15) & ~15); }
  ParamTab tab;
  for (int i = 0; i < 15; i++){ tab.src[i] = d_in[3 + i]; tab.dst[i] = prm + poff[i]; tab.sz[i] = psz[i]; }
  tab.sz[14] = 5;
  const float* c_cw   = prm + poff[0];
  const float* c_cb   = prm + poff[1];
  const float* c_lw   = prm + poff[2];
  const float* c_lb   = prm + poff[3];
  const float* c_lsw  = prm + poff[4];
  const float* c_lsb  = prm + poff[5];
  const float* c_slw  = prm + poff[6];
  const float* c_slb  = prm + poff[7];
  const float* c_srw  = prm + poff[8];
  const float* c_lng  = prm + poff[9];
  const float* c_lnb  = prm + poff[10];
  const float* c_m1w  = prm + poff[11];
  const float* c_m1b  = prm + poff[12];
  const float* c_m2w  = prm + poff[13];
  const float* c_m2b  = prm + poff[14];

  hipMemsetAsync(degI, 0, (size_t)NN*4, stream);
  sniff_kernel<<<1, 256, 0, stream>>>((const int*)eraw, (const u16*)x, flg);
  canon_params_kernel<<<15, 256, 0, stream>>>(tab, flg);
  convert_edges_kernel<<<(2*EE + 255)/256, 256, 0, stream>>>(eraw, edg, flg, 2*EE);
  conv_relu_kernel<<<NN, 256, 0, stream>>>(x, bd, c_cw, c_cb, flg, h0);
  deg_kernel<<<(EE + 255)/256, 256, 0, stream>>>(edst, degI, EE);
  invdeg_kernel<<<(NN + 255)/256, 256, 0, stream>>>(degI, invd, NN);
  scan_kernel<<<1, 1024, 0, stream>>>(degI, rowp, curs, NN);
  bucket_kernel<<<(EE + 255)/256, 256, 0, stream>>>(esrc, edst, curs, ebuc, EE);

  dim3 ggrid((NN + 63)/64, 4);
  const int agrid = (NN + 3)/4;
  // layer 0: self_x -> bufA, neigh -> bufB, then bufA[n] += sum_in bufB[src]
  gemm_fused_kernel<<<ggrid, 256, 0, stream>>>(h0, 656, c_lsw, 652,
      nullptr, 0, nullptr, 0, c_lsb, bufA, nullptr, nullptr, flg, NN);
  gemm_fused_kernel<<<ggrid, 256, 0, stream>>>(h0, 656, c_lw, 652,
      nullptr, 0, nullptr, 0, c_lb, bufB, nullptr, nullptr, flg, NN);
  gather_agg_kernel<<<agrid, 256, 0, stream>>>(bufB, bufA, nullptr, bufA, rowp, ebuc);

  // SAGE layers: h in bufA; mean-agg (pre-scaled by invd) in bufC; gemm -> bufB
  for (int i = 0; i < 3; i++){
    gather_agg_kernel<<<agrid, 256, 0, stream>>>(bufA, nullptr, invd, bufC, rowp, ebuc);
    const float* L  = c_slw + (size_t)i*256*256;
    const float* Lb = c_slb + (size_t)i*256;
    const float* R  = c_srw + (size_t)i*256*256;
    if (i < 2){
      gemm_fused_kernel<<<ggrid, 256, 0, stream>>>(bufC, 256, L, 256,
          bufA, 256, R, 256, Lb, bufB, nullptr, nullptr, flg, NN);
      relu_ln_kernel<<<NN, 256, 0, stream>>>(bufB, bufA,
          c_lng + (size_t)i*256, c_lnb + (size_t)i*256);
    } else {
      gemm_fused_kernel<<<ggrid, 256, 0, stream>>>(bufC, 256, L, 256,
          bufA, 256, R, 256, Lb, nullptr, d_out, bufB, flg, NN);
    }
  }
  gemm_fused_kernel<<<ggrid, 256, 0, stream>>>(bufB, 256, c_m1w, 256,
      nullptr, 0, nullptr, 0, c_m1b, bufC, nullptr, nullptr, flg, NN);
  head_kernel<<<(NN + 255)/256, 256, 0, stream>>>(bufC, c_m2w, c_m2b,
      d_out, (size_t)NN*256, flg, NN);
}

// Round 4
// 1474.536 us; speedup vs baseline: 8.5665x; 1.6999x over previous
//
#include <hip/hip_runtime.h>
#include <hip/hip_bf16.h>
#include <stdint.h>

#define NN 50000
#define EE 800000

typedef unsigned short u16;
typedef __attribute__((ext_vector_type(4))) float f32x4;
typedef __attribute__((ext_vector_type(8))) short bf16x8;

__device__ __forceinline__ float bu2f(u16 u){ return __uint_as_float(((unsigned)u)<<16); }
__device__ __forceinline__ u16 f2bu(float f){
  unsigned u = __float_as_uint(f);
  u += 0x7fffu + ((u>>16)&1u);      // round-to-nearest-even
  return (u16)(u>>16);
}

// ---------- sniff: flags[0] = edges are int64; flags[1] = float inputs are bf16 ----------
__global__ void sniff_kernel(const int* __restrict__ e, const u16* __restrict__ xu,
                             int* __restrict__ flags){
  __shared__ int nz, cnt;
  int t = threadIdx.x;
  if (t == 0){ nz = 0; cnt = 0; }
  __syncthreads();
  if (e[2*t + 1] != 0) atomicOr(&nz, 1);
  u16 u = xu[2*t];
  int ef = (u >> 7) & 0xFF;
  int ok = (u == 0) || (ef >= 118 && ef <= 132);
  atomicAdd(&cnt, ok);
  __syncthreads();
  if (t == 0){ flags[0] = (nz == 0) ? 1 : 0; flags[1] = (cnt >= 200) ? 1 : 0; }
}

__global__ void convert_edges_kernel(const void* __restrict__ ep, int* __restrict__ outp,
                                     const int* __restrict__ flags, int total){
  int i = blockIdx.x*256 + threadIdx.x;
  if (i >= total) return;
  if (flags[0]) outp[i] = (int)((const long long*)ep)[i];
  else          outp[i] = ((const int*)ep)[i];
}

// ---------- canonicalize params: optional K-pad, to bf16 or fp32 ----------
struct CanonTab {
  const void* src[15];
  void*       dst[15];
  int rows[15];
  int sk[15];
  int dk[15];
  int tobf[15];
};

__global__ __launch_bounds__(256) void canon_params_kernel(CanonTab tab, const int* __restrict__ flags){
  int a = blockIdx.x;
  int isbf = flags[1];
  int rows = tab.rows[a], sk = tab.sk[a], dk = tab.dk[a], tobf = tab.tobf[a];
  int n = rows * dk;
  for (int i = threadIdx.x; i < n; i += 256){
    int r = i / dk, c = i % dk;
    float v = 0.f;
    if (c < sk){
      size_t si = (size_t)r*sk + c;
      v = isbf ? bu2f(((const u16*)tab.src[a])[si]) : ((const float*)tab.src[a])[si];
    }
    if (tobf) ((u16*)tab.dst[a])[i] = f2bu(v);
    else      ((float*)tab.dst[a])[i] = v;
  }
}

// ---------- conv3x3 VALID + bias + concat(bd) + relu -> h0 bf16 [NN][672] (cols 652..671 zero) ----
// lane mapping: j = pos*?   within a wave, j=base+t -> co = j&7 (channel), pos = j>>3
// => 8 distinct xs addresses per FMA (8-lane broadcast each), conflict-free.
__global__ __launch_bounds__(256) void conv_relu_kernel(
    const void* __restrict__ xraw, const void* __restrict__ bdraw,
    const float* __restrict__ cw, const float* __restrict__ cb,
    const int* __restrict__ flags, u16* __restrict__ h0){
  __shared__ float xs[968];    // 8*121
  __shared__ float wsm[576];   // 8*8*9
  __shared__ float bs[8];
  int n = blockIdx.x, t = threadIdx.x;
  int isbf = flags[1];
  if (isbf){
    const ushort4* xp = (const ushort4*)((const u16*)xraw + (size_t)n*968);
    if (t < 242){ ushort4 u = xp[t]; xs[4*t]=bu2f(u.x); xs[4*t+1]=bu2f(u.y); xs[4*t+2]=bu2f(u.z); xs[4*t+3]=bu2f(u.w); }
  } else {
    const float4* xp = (const float4*)((const float*)xraw + (size_t)n*968);
    if (t < 242){ float4 u = xp[t]; xs[4*t]=u.x; xs[4*t+1]=u.y; xs[4*t+2]=u.z; xs[4*t+3]=u.w; }
  }
  if (t < 144){ float4 u = ((const float4*)cw)[t]; wsm[4*t]=u.x; wsm[4*t+1]=u.y; wsm[4*t+2]=u.z; wsm[4*t+3]=u.w; }
  if (t < 8) bs[t] = cb[t];
  __syncthreads();
  u16* outr = h0 + (size_t)n*672;
  for (int base = 0; base < 672; base += 256){
    int j = base + t;
    if (j >= 672) continue;
    float v; int outcol;
    if (j < 648){
      int co = j & 7, pos = j >> 3;
      int oi = pos/9, oj = pos%9;
      outcol = co*81 + pos;
      float acc = bs[co];
      const float* wp = wsm + co*72;
      const float* xb = xs + oi*11 + oj;
      #pragma unroll
      for (int ci=0; ci<8; ci++)
        #pragma unroll
        for (int ki=0; ki<3; ki++)
          #pragma unroll
          for (int kj=0; kj<3; kj++)
            acc += xb[ci*121 + ki*11 + kj] * wp[ci*9 + ki*3 + kj];
      v = acc;
    } else if (j < 652){
      outcol = j;
      int jj = j - 648;
      v = isbf ? bu2f(((const u16*)bdraw)[(size_t)n*4 + jj]) : ((const float*)bdraw)[(size_t)n*4 + jj];
    } else {
      outcol = j; v = 0.f;
    }
    outr[outcol] = f2bu(fmaxf(v, 0.f));
  }
}

// ---------- degree ----------
__global__ void deg_kernel(const int* __restrict__ dst, int* __restrict__ degI, int E){
  int e = blockIdx.x*256 + threadIdx.x;
  if (e < E) atomicAdd(&degI[dst[e]], 1);
}
__global__ void invdeg_kernel(const int* __restrict__ degI, float* __restrict__ inv, int n){
  int i = blockIdx.x*256 + threadIdx.x;
  if (i < n){ int d = degI[i]; inv[i] = 1.0f / (float)(d > 1 ? d : 1); }
}

// ---------- exclusive scan of degI -> rowptr (single block, 1024 threads) ----------
__global__ __launch_bounds__(1024) void scan_kernel(const int* __restrict__ degI,
                                                    int* __restrict__ rowptr,
                                                    int* __restrict__ cursor, int n){
  __shared__ int warp_sums[16];
  __shared__ int carry;
  int t = threadIdx.x;
  if (t == 0) carry = 0;
  __syncthreads();
  for (int base = 0; base < n; base += 1024){
    int i = base + t;
    int v = (i < n) ? degI[i] : 0;
    int s = v;
    #pragma unroll
    for (int off = 1; off < 64; off <<= 1){ int u = __shfl_up(s, off); if ((t & 63) >= off) s += u; }
    if ((t & 63) == 63) warp_sums[t >> 6] = s;
    __syncthreads();
    if (t < 16){
      int wsv = warp_sums[t];
      #pragma unroll
      for (int off = 1; off < 16; off <<= 1){ int u = __shfl_up(wsv, off); if (t >= off) wsv += u; }
      warp_sums[t] = wsv;
    }
    __syncthreads();
    int block_off = (t >= 64) ? warp_sums[(t >> 6) - 1] : 0;
    int excl = carry + block_off + s - v;
    if (i < n){ rowptr[i] = excl; cursor[i] = excl; }
    int total = warp_sums[15];
    __syncthreads();
    if (t == 0) carry += total;
    __syncthreads();
  }
  if (t == 0) rowptr[n] = carry;
}

// ---------- bucket fill: ebuc[cursor[dst]++] = src ----------
__global__ void bucket_kernel(const int* __restrict__ esrc, const int* __restrict__ edst,
                              int* __restrict__ cursor, int* __restrict__ ebuc, int E){
  int e = blockIdx.x*256 + threadIdx.x;
  if (e < E){ int pos = atomicAdd(&cursor[edst[e]], 1); ebuc[pos] = esrc[e]; }
}

// ---------- gather-aggregate (bf16): out[n] = (addbase?addbase[n]:0) + scale[n]*sum src[nbr] ----
__global__ __launch_bounds__(256) void gather_agg_kernel(
    const u16* __restrict__ src_feat, const u16* __restrict__ addbase,
    const float* __restrict__ scale, u16* __restrict__ outp,
    const int* __restrict__ rowptr, const int* __restrict__ ebuc){
  int wid = threadIdx.x >> 6, lane = threadIdx.x & 63;
  int n = blockIdx.x*4 + wid;
  if (n >= NN) return;
  int beg = rowptr[n], end = rowptr[n+1];
  float a0=0.f,a1=0.f,a2=0.f,a3=0.f;
  float b0=0.f,b1=0.f,b2=0.f,b3=0.f;
  int j = beg;
  for (; j + 1 < end; j += 2){
    int s0 = ebuc[j], s1 = ebuc[j+1];
    ushort4 v0 = *(const ushort4*)(src_feat + (size_t)s0*256 + lane*4);
    ushort4 v1 = *(const ushort4*)(src_feat + (size_t)s1*256 + lane*4);
    a0 += bu2f(v0.x); a1 += bu2f(v0.y); a2 += bu2f(v0.z); a3 += bu2f(v0.w);
    b0 += bu2f(v1.x); b1 += bu2f(v1.y); b2 += bu2f(v1.z); b3 += bu2f(v1.w);
  }
  if (j < end){
    ushort4 v0 = *(const ushort4*)(src_feat + (size_t)ebuc[j]*256 + lane*4);
    a0 += bu2f(v0.x); a1 += bu2f(v0.y); a2 += bu2f(v0.z); a3 += bu2f(v0.w);
  }
  float sc = scale ? scale[n] : 1.f;
  a0 = (a0+b0)*sc; a1 = (a1+b1)*sc; a2 = (a2+b2)*sc; a3 = (a3+b3)*sc;
  if (addbase){
    ushort4 b = *(const ushort4*)(addbase + (size_t)n*256 + lane*4);
    a0 += bu2f(b.x); a1 += bu2f(b.y); a2 += bu2f(b.z); a3 += bu2f(b.w);
  }
  ushort4 o; o.x = f2bu(a0); o.y = f2bu(a1); o.z = f2bu(a2); o.w = f2bu(a3);
  *(ushort4*)(outp + (size_t)n*256 + lane*4) = o;
}

// ---------- MFMA bf16 GEMM: out = (A1 @ W1^T) + (A2 @ W2^T) + bias ----------
// A bf16 [M][lda], W bf16 [256][K] row-major, K % 32 == 0. Tile 128x128, 4 waves 2x2.
__global__ __launch_bounds__(256) void gemm_mfma_kernel(
    const u16* __restrict__ A1, int lda1, const u16* __restrict__ W1, int K1,
    const u16* __restrict__ A2, int lda2, const u16* __restrict__ W2, int K2,
    const float* __restrict__ bias,
    u16* __restrict__ out_bf,
    void* __restrict__ out_emb,
    u16* __restrict__ out_relu_bf,
    const int* __restrict__ flags, int M){
  __shared__ u16 Asm[128][40];   // pad 32->40: frag reads hit each bank exactly 2x (free)
  __shared__ u16 Wsm[128][40];
  int t = threadIdx.x;
  int wave = t >> 6, lane = t & 63;
  int wr = wave >> 1, wc = wave & 1;
  int m0 = blockIdx.x << 7;
  int o0 = blockIdx.y << 7;
  int lrow = t >> 1;            // staging row 0..127
  int lk8  = (t & 1) << 3;      // staging k offset 0/8 (plus +16 second load)
  int fr = lane & 15;           // fragment row/col
  int fk = (lane >> 4) << 3;    // fragment k base
  f32x4 acc[4][4] = {};

  for (int pass = 0; pass < 2; ++pass){
    const u16* A; const u16* W; int K, lda;
    if (pass == 0){ A = A1; W = W1; K = K1; lda = lda1; }
    else { if (!A2) break; A = A2; W = W2; K = K2; lda = lda2; }
    for (int k0 = 0; k0 < K; k0 += 32){
      int gm = m0 + lrow;
      int4 av0 = make_int4(0,0,0,0), av1 = av0;
      if (gm < M){
        const int4* ap = (const int4*)(A + (size_t)gm*lda + k0 + lk8);
        av0 = ap[0];
        av1 = ap[2];     // +16 elements
      }
      const int4* wp = (const int4*)(W + (size_t)(o0 + lrow)*K + k0 + lk8);
      int4 wv0 = wp[0];
      int4 wv1 = wp[2];
      *(int4*)&Asm[lrow][lk8]      = av0;
      *(int4*)&Asm[lrow][lk8+16]   = av1;
      *(int4*)&Wsm[lrow][lk8]      = wv0;
      *(int4*)&Wsm[lrow][lk8+16]   = wv1;
      __syncthreads();
      bf16x8 af[4], wf[4];
      #pragma unroll
      for (int i = 0; i < 4; i++) af[i] = *(const bf16x8*)&Asm[wr*64 + i*16 + fr][fk];
      #pragma unroll
      for (int jj = 0; jj < 4; jj++) wf[jj] = *(const bf16x8*)&Wsm[wc*64 + jj*16 + fr][fk];
      #pragma unroll
      for (int i = 0; i < 4; i++)
        #pragma unroll
        for (int jj = 0; jj < 4; jj++)
          acc[i][jj] = __builtin_amdgcn_mfma_f32_16x16x32_bf16(af[i], wf[jj], acc[i][jj], 0, 0, 0);
      __syncthreads();
    }
  }
  int isbf = flags[1];
  int fg = lane >> 4;
  #pragma unroll
  for (int i = 0; i < 4; i++){
    int rbase = m0 + wr*64 + i*16 + fg*4;
    #pragma unroll
    for (int jj = 0; jj < 4; jj++){
      int col = o0 + wc*64 + jj*16 + fr;
      float bv = bias[col];
      #pragma unroll
      for (int r = 0; r < 4; r++){
        int row = rbase + r;
        if (row < M){
          float v = acc[i][jj][r] + bv;
          size_t off = (size_t)row*256 + col;
          if (out_bf)   out_bf[off] = f2bu(v);
          if (out_emb){
            if (isbf) ((u16*)out_emb)[off] = f2bu(v);
            else      ((float*)out_emb)[off] = v;
          }
          if (out_relu_bf) out_relu_bf[off] = f2bu(fmaxf(v, 0.f));
        }
      }
    }
  }
}

// ---------- relu + layernorm (bf16 in/out) ----------
__global__ __launch_bounds__(256) void relu_ln_kernel(
    const u16* __restrict__ inb, u16* __restrict__ outb,
    const float* __restrict__ g, const float* __restrict__ b){
  __shared__ float rs[4], rs2[4];
  int n = blockIdx.x, t = threadIdx.x;
  float v = fmaxf(bu2f(inb[(size_t)n*256 + t]), 0.f);
  float s = v, s2 = v*v;
  #pragma unroll
  for (int off = 1; off < 64; off <<= 1){ s += __shfl_xor(s, off); s2 += __shfl_xor(s2, off); }
  if ((t & 63) == 0){ rs[t>>6] = s; rs2[t>>6] = s2; }
  __syncthreads();
  float S  = rs[0]+rs[1]+rs[2]+rs[3];
  float S2 = rs2[0]+rs2[1]+rs2[2]+rs2[3];
  float mu  = S * (1.f/256.f);
  float var = S2 * (1.f/256.f) - mu*mu;
  float inv = rsqrtf(var + 1e-5f);
  outb[(size_t)n*256 + t] = f2bu((v - mu) * inv * g[t] + b[t]);
}

// ---------- head: z2 = z1 @ mp2^T + b2; log_softmax ----------
__global__ __launch_bounds__(256) void head_kernel(
    const u16* __restrict__ z1, const float* __restrict__ w2, const float* __restrict__ b2,
    void* __restrict__ outbase, size_t out_off, const int* __restrict__ flags, int M){
  __shared__ float wsm[1280];
  __shared__ float bs[5];
  int t = threadIdx.x;
  for (int i = t; i < 320; i += 256){
    float4 u = ((const float4*)w2)[i];
    wsm[4*i]=u.x; wsm[4*i+1]=u.y; wsm[4*i+2]=u.z; wsm[4*i+3]=u.w;
  }
  if (t < 5) bs[t] = b2[t];
  __syncthreads();
  int n = blockIdx.x*256 + t;
  if (n >= M) return;
  const u16* zp = z1 + (size_t)n*256;
  float acc[5];
  #pragma unroll
  for (int o = 0; o < 5; o++) acc[o] = bs[o];
  for (int k = 0; k < 256; k += 4){
    ushort4 zu = *(const ushort4*)(zp + k);
    float z0 = bu2f(zu.x), z1f = bu2f(zu.y), z2 = bu2f(zu.z), z3 = bu2f(zu.w);
    #pragma unroll
    for (int o = 0; o < 5; o++){
      const float* w = wsm + o*256 + k;
      acc[o] += z0*w[0] + z1f*w[1] + z2*w[2] + z3*w[3];
    }
  }
  float mx = acc[0];
  #pragma unroll
  for (int o = 1; o < 5; o++) mx = fmaxf(mx, acc[o]);
  float se = 0.f;
  #pragma unroll
  for (int o = 0; o < 5; o++) se += expf(acc[o] - mx);
  float lse = mx + logf(se);
  int isbf = flags[1];
  if (isbf){
    u16* op = (u16*)outbase + out_off + (size_t)n*5;
    #pragma unroll
    for (int o = 0; o < 5; o++) op[o] = f2bu(acc[o] - lse);
  } else {
    float* op = (float*)outbase + out_off + (size_t)n*5;
    #pragma unroll
    for (int o = 0; o < 5; o++) op[o] = acc[o] - lse;
  }
}

extern "C" void kernel_launch(void* const* d_in, const int* in_sizes, int n_in,
                              void* d_out, int out_size, void* d_ws, size_t ws_size,
                              hipStream_t stream){
  (void)in_sizes; (void)n_in; (void)out_size; (void)ws_size;
  const void* x    = d_in[0];
  const void* bd   = d_in[1];
  const void* eraw = d_in[2];

  char* ws = (char*)d_ws;
  const size_t OFF_H0 = 0;                                    // bf16 [NN][672]
  const size_t OFF_A  = OFF_H0 + (size_t)NN*672*2;            // bf16 [NN][256]
  const size_t OFF_B  = OFF_A  + (size_t)NN*256*2;
  const size_t OFF_C  = OFF_B  + (size_t)NN*256*2;
  const size_t OFF_DEG= OFF_C  + (size_t)NN*256*2;
  const size_t OFF_INV= OFF_DEG + (size_t)NN*4;
  const size_t OFF_EDG= OFF_INV + (size_t)NN*4;
  const size_t OFF_RP = OFF_EDG + (size_t)2*EE*4;
  const size_t OFF_CUR= OFF_RP  + (size_t)(NN+16)*4;
  const size_t OFF_EBU= OFF_CUR + (size_t)NN*4;
  const size_t OFF_FLG= OFF_EBU + (size_t)EE*4;
  const size_t OFF_PRM= OFF_FLG + 256;

  u16*   h0   = (u16*)(ws + OFF_H0);
  u16*   bufA = (u16*)(ws + OFF_A);
  u16*   bufB = (u16*)(ws + OFF_B);
  u16*   bufC = (u16*)(ws + OFF_C);
  int*   degI = (int*)(ws + OFF_DEG);
  float* invd = (float*)(ws + OFF_INV);
  int*   edg  = (int*)(ws + OFF_EDG);
  int*   rowp = (int*)(ws + OFF_RP);
  int*   curs = (int*)(ws + OFF_CUR);
  int*   ebuc = (int*)(ws + OFF_EBU);
  int*   flg  = (int*)(ws + OFF_FLG);
  char*  prm  = ws + OFF_PRM;
  const int* esrc = edg;
  const int* edst = edg + EE;

  // canon entries: {rows, srcK, dstK, tobf}
  static const int crows[15] = {1,1,256,1,256,1,1,1,1,1,1,1,1,1,1};
  static const int csk[15]   = {576,8,652,256,652,256,196608,768,196608,512,512,65536,256,1280,5};
  static const int cdk[15]   = {576,8,672,256,672,256,196608,768,196608,512,512,65536,256,1280,5};
  static const int ctobf[15] = {0,0,1,0,1,0,1,0,1,0,0,1,0,0,0};
  CanonTab tab;
  size_t po = 0;
  void* dsts[15];
  for (int i = 0; i < 15; i++){
    tab.src[i] = d_in[3+i];
    tab.rows[i] = crows[i]; tab.sk[i] = csk[i]; tab.dk[i] = cdk[i]; tab.tobf[i] = ctobf[i];
    dsts[i] = prm + po;
    tab.dst[i] = dsts[i];
    size_t bytes = (size_t)crows[i]*cdk[i] * (ctobf[i] ? 2 : 4);
    po += (bytes + 63) & ~(size_t)63;
  }
  const float* c_cw  = (const float*)dsts[0];
  const float* c_cb  = (const float*)dsts[1];
  const u16*   c_lw  = (const u16*)dsts[2];
  const float* c_lb  = (const float*)dsts[3];
  const u16*   c_lsw = (const u16*)dsts[4];
  const float* c_lsb = (const float*)dsts[5];
  const u16*   c_slw = (const u16*)dsts[6];
  const float* c_slb = (const float*)dsts[7];
  const u16*   c_srw = (const u16*)dsts[8];
  const float* c_lng = (const float*)dsts[9];
  const float* c_lnb = (const float*)dsts[10];
  const u16*   c_m1w = (const u16*)dsts[11];
  const float* c_m1b = (const float*)dsts[12];
  const float* c_m2w = (const float*)dsts[13];
  const float* c_m2b = (const float*)dsts[14];

  hipMemsetAsync(degI, 0, (size_t)NN*4, stream);
  sniff_kernel<<<1, 256, 0, stream>>>((const int*)eraw, (const u16*)x, flg);
  canon_params_kernel<<<15, 256, 0, stream>>>(tab, flg);
  convert_edges_kernel<<<(2*EE + 255)/256, 256, 0, stream>>>(eraw, edg, flg, 2*EE);
  conv_relu_kernel<<<NN, 256, 0, stream>>>(x, bd, c_cw, c_cb, flg, h0);
  deg_kernel<<<(EE + 255)/256, 256, 0, stream>>>(edst, degI, EE);
  invdeg_kernel<<<(NN + 255)/256, 256, 0, stream>>>(degI, invd, NN);
  scan_kernel<<<1, 1024, 0, stream>>>(degI, rowp, curs, NN);
  bucket_kernel<<<(EE + 255)/256, 256, 0, stream>>>(esrc, edst, curs, ebuc, EE);

  dim3 ggrid((NN + 127)/128, 2);
  const int agrid = (NN + 3)/4;
  // layer 0: self_x -> bufA, neigh -> bufB, then bufA[n] += sum_in bufB[src]
  gemm_mfma_kernel<<<ggrid, 256, 0, stream>>>(h0, 672, c_lsw, 672,
      nullptr, 0, nullptr, 0, c_lsb, bufA, nullptr, nullptr, flg, NN);
  gemm_mfma_kernel<<<ggrid, 256, 0, stream>>>(h0, 672, c_lw, 672,
      nullptr, 0, nullptr, 0, c_lb, bufB, nullptr, nullptr, flg, NN);
  gather_agg_kernel<<<agrid, 256, 0, stream>>>(bufB, bufA, nullptr, bufA, rowp, ebuc);

  // SAGE layers: h in bufA; mean-agg (pre-scaled by invd) in bufC; gemm -> bufB
  for (int i = 0; i < 3; i++){
    gather_agg_kernel<<<agrid, 256, 0, stream>>>(bufA, nullptr, invd, bufC, rowp, ebuc);
    const u16*   L  = c_slw + (size_t)i*256*256;
    const float* Lb = c_slb + (size_t)i*256;
    const u16*   R  = c_srw + (size_t)i*256*256;
    if (i < 2){
      gemm_mfma_kernel<<<ggrid, 256, 0, stream>>>(bufC, 256, L, 256,
          bufA, 256, R, 256, Lb, bufB, nullptr, nullptr, flg, NN);
      relu_ln_kernel<<<NN, 256, 0, stream>>>(bufB, bufA,
          c_lng + (size_t)i*256, c_lnb + (size_t)i*256);
    } else {
      gemm_mfma_kernel<<<ggrid, 256, 0, stream>>>(bufC, 256, L, 256,
          bufA, 256, R, 256, Lb, nullptr, d_out, bufB, flg, NN);
    }
  }
  gemm_mfma_kernel<<<ggrid, 256, 0, stream>>>(bufB, 256, c_m1w, 256,
      nullptr, 0, nullptr, 0, c_m1b, bufC, nullptr, nullptr, flg, NN);
  head_kernel<<<(NN + 255)/256, 256, 0, stream>>>(bufC, c_m2w, c_m2b,
      d_out, (size_t)NN*256, flg, NN);
}

// Round 5
// 1016.383 us; speedup vs baseline: 12.4280x; 1.4508x over previous
//
#include <hip/hip_runtime.h>
#include <hip/hip_bf16.h>
#include <stdint.h>

#define NN 50000
#define EE 800000

typedef unsigned short u16;
typedef __attribute__((ext_vector_type(4))) float f32x4;
typedef __attribute__((ext_vector_type(8))) short bf16x8;

__device__ __forceinline__ float bu2f(u16 u){ return __uint_as_float(((unsigned)u)<<16); }
__device__ __forceinline__ u16 f2bu(float f){
  unsigned u = __float_as_uint(f);
  u += 0x7fffu + ((u>>16)&1u);      // round-to-nearest-even
  return (u16)(u>>16);
}

// ---------- sniff: flags[0] = edges are int64; flags[1] = float inputs are bf16 ----------
__global__ void sniff_kernel(const int* __restrict__ e, const u16* __restrict__ xu,
                             int* __restrict__ flags){
  __shared__ int nz, cnt;
  int t = threadIdx.x;
  if (t == 0){ nz = 0; cnt = 0; }
  __syncthreads();
  if (e[2*t + 1] != 0) atomicOr(&nz, 1);
  u16 u = xu[2*t];
  int ef = (u >> 7) & 0xFF;
  int ok = (u == 0) || (ef >= 118 && ef <= 132);
  atomicAdd(&cnt, ok);
  __syncthreads();
  if (t == 0){ flags[0] = (nz == 0) ? 1 : 0; flags[1] = (cnt >= 200) ? 1 : 0; }
}

__global__ void convert_edges_kernel(const void* __restrict__ ep, int* __restrict__ outp,
                                     const int* __restrict__ flags, int total){
  int i = blockIdx.x*256 + threadIdx.x;
  if (i >= total) return;
  if (flags[0]) outp[i] = (int)((const long long*)ep)[i];
  else          outp[i] = ((const int*)ep)[i];
}

// ---------- canonicalize params: optional K-pad, to bf16 or fp32 ----------
// grid = (96 chunks, 15 params); 8 elements/thread -> massively parallel, off critical path.
struct CanonTab {
  const void* src[15];
  void*       dst[15];
  int rows[15];
  int sk[15];
  int dk[15];
  int tobf[15];
};

__global__ __launch_bounds__(256) void canon_params_kernel(CanonTab tab, const int* __restrict__ flags){
  int a = blockIdx.y;
  int isbf = flags[1];
  int rows = tab.rows[a], sk = tab.sk[a], dk = tab.dk[a], tobf = tab.tobf[a];
  int n = rows * dk;
  int base = (blockIdx.x*256 + threadIdx.x) * 8;
  if (base >= n) return;
  #pragma unroll
  for (int uu = 0; uu < 8; uu++){
    int i = base + uu;
    if (i >= n) break;
    int r = i / dk, c = i - r*dk;
    float v = 0.f;
    if (c < sk){
      size_t si = (size_t)r*sk + c;
      v = isbf ? bu2f(((const u16*)tab.src[a])[si]) : ((const float*)tab.src[a])[si];
    }
    if (tobf) ((u16*)tab.dst[a])[i] = f2bu(v);
    else      ((float*)tab.dst[a])[i] = v;
  }
}

// ---------- conv3x3 VALID + bias + concat(bd) + relu -> h0 bf16 [NN][672] (cols 652..671 zero) ----
__global__ __launch_bounds__(256) void conv_relu_kernel(
    const void* __restrict__ xraw, const void* __restrict__ bdraw,
    const float* __restrict__ cw, const float* __restrict__ cb,
    const int* __restrict__ flags, u16* __restrict__ h0){
  __shared__ float xs[968];    // 8*121
  __shared__ float wsm[576];   // 8*8*9
  __shared__ float bs[8];
  int n = blockIdx.x, t = threadIdx.x;
  int isbf = flags[1];
  if (isbf){
    const ushort4* xp = (const ushort4*)((const u16*)xraw + (size_t)n*968);
    if (t < 242){ ushort4 u = xp[t]; xs[4*t]=bu2f(u.x); xs[4*t+1]=bu2f(u.y); xs[4*t+2]=bu2f(u.z); xs[4*t+3]=bu2f(u.w); }
  } else {
    const float4* xp = (const float4*)((const float*)xraw + (size_t)n*968);
    if (t < 242){ float4 u = xp[t]; xs[4*t]=u.x; xs[4*t+1]=u.y; xs[4*t+2]=u.z; xs[4*t+3]=u.w; }
  }
  if (t < 144){ float4 u = ((const float4*)cw)[t]; wsm[4*t]=u.x; wsm[4*t+1]=u.y; wsm[4*t+2]=u.z; wsm[4*t+3]=u.w; }
  if (t < 8) bs[t] = cb[t];
  __syncthreads();
  u16* outr = h0 + (size_t)n*672;
  for (int base = 0; base < 672; base += 256){
    int j = base + t;
    if (j >= 672) continue;
    float v; int outcol;
    if (j < 648){
      int co = j & 7, pos = j >> 3;
      int oi = pos/9, oj = pos%9;
      outcol = co*81 + pos;
      float acc = bs[co];
      const float* wp = wsm + co*72;
      const float* xb = xs + oi*11 + oj;
      #pragma unroll
      for (int ci=0; ci<8; ci++)
        #pragma unroll
        for (int ki=0; ki<3; ki++)
          #pragma unroll
          for (int kj=0; kj<3; kj++)
            acc += xb[ci*121 + ki*11 + kj] * wp[ci*9 + ki*3 + kj];
      v = acc;
    } else if (j < 652){
      outcol = j;
      int jj = j - 648;
      v = isbf ? bu2f(((const u16*)bdraw)[(size_t)n*4 + jj]) : ((const float*)bdraw)[(size_t)n*4 + jj];
    } else {
      outcol = j; v = 0.f;
    }
    outr[outcol] = f2bu(fmaxf(v, 0.f));
  }
}

// ---------- degree ----------
__global__ void deg_kernel(const int* __restrict__ dst, int* __restrict__ degI, int E){
  int e = blockIdx.x*256 + threadIdx.x;
  if (e < E) atomicAdd(&degI[dst[e]], 1);
}
__global__ void invdeg_kernel(const int* __restrict__ degI, float* __restrict__ inv, int n){
  int i = blockIdx.x*256 + threadIdx.x;
  if (i < n){ int d = degI[i]; inv[i] = 1.0f / (float)(d > 1 ? d : 1); }
}

// ---------- exclusive scan of degI -> rowptr (single block, 1024 threads) ----------
__global__ __launch_bounds__(1024) void scan_kernel(const int* __restrict__ degI,
                                                    int* __restrict__ rowptr,
                                                    int* __restrict__ cursor, int n){
  __shared__ int warp_sums[16];
  __shared__ int carry;
  int t = threadIdx.x;
  if (t == 0) carry = 0;
  __syncthreads();
  for (int base = 0; base < n; base += 1024){
    int i = base + t;
    int v = (i < n) ? degI[i] : 0;
    int s = v;
    #pragma unroll
    for (int off = 1; off < 64; off <<= 1){ int u = __shfl_up(s, off); if ((t & 63) >= off) s += u; }
    if ((t & 63) == 63) warp_sums[t >> 6] = s;
    __syncthreads();
    if (t < 16){
      int wsv = warp_sums[t];
      #pragma unroll
      for (int off = 1; off < 16; off <<= 1){ int u = __shfl_up(wsv, off); if (t >= off) wsv += u; }
      warp_sums[t] = wsv;
    }
    __syncthreads();
    int block_off = (t >= 64) ? warp_sums[(t >> 6) - 1] : 0;
    int excl = carry + block_off + s - v;
    if (i < n){ rowptr[i] = excl; cursor[i] = excl; }
    int total = warp_sums[15];
    __syncthreads();
    if (t == 0) carry += total;
    __syncthreads();
  }
  if (t == 0) rowptr[n] = carry;
}

// ---------- bucket fill: ebuc[cursor[dst]++] = src ----------
__global__ void bucket_kernel(const int* __restrict__ esrc, const int* __restrict__ edst,
                              int* __restrict__ cursor, int* __restrict__ ebuc, int E){
  int e = blockIdx.x*256 + threadIdx.x;
  if (e < E){ int pos = atomicAdd(&cursor[edst[e]], 1); ebuc[pos] = esrc[e]; }
}

// ---------- gather-aggregate (bf16): out[n] = (addbase?addbase[n]:0) + scale[n]*sum src[nbr] ----
__global__ __launch_bounds__(256) void gather_agg_kernel(
    const u16* __restrict__ src_feat, const u16* __restrict__ addbase,
    const float* __restrict__ scale, u16* __restrict__ outp,
    const int* __restrict__ rowptr, const int* __restrict__ ebuc){
  int wid = threadIdx.x >> 6, lane = threadIdx.x & 63;
  int n = blockIdx.x*4 + wid;
  if (n >= NN) return;
  int beg = rowptr[n], end = rowptr[n+1];
  float a0=0.f,a1=0.f,a2=0.f,a3=0.f;
  float b0=0.f,b1=0.f,b2=0.f,b3=0.f;
  int j = beg;
  for (; j + 1 < end; j += 2){
    int s0 = ebuc[j], s1 = ebuc[j+1];
    ushort4 v0 = *(const ushort4*)(src_feat + (size_t)s0*256 + lane*4);
    ushort4 v1 = *(const ushort4*)(src_feat + (size_t)s1*256 + lane*4);
    a0 += bu2f(v0.x); a1 += bu2f(v0.y); a2 += bu2f(v0.z); a3 += bu2f(v0.w);
    b0 += bu2f(v1.x); b1 += bu2f(v1.y); b2 += bu2f(v1.z); b3 += bu2f(v1.w);
  }
  if (j < end){
    ushort4 v0 = *(const ushort4*)(src_feat + (size_t)ebuc[j]*256 + lane*4);
    a0 += bu2f(v0.x); a1 += bu2f(v0.y); a2 += bu2f(v0.z); a3 += bu2f(v0.w);
  }
  float sc = scale ? scale[n] : 1.f;
  a0 = (a0+b0)*sc; a1 = (a1+b1)*sc; a2 = (a2+b2)*sc; a3 = (a3+b3)*sc;
  if (addbase){
    ushort4 b = *(const ushort4*)(addbase + (size_t)n*256 + lane*4);
    a0 += bu2f(b.x); a1 += bu2f(b.y); a2 += bu2f(b.z); a3 += bu2f(b.w);
  }
  ushort4 o; o.x = f2bu(a0); o.y = f2bu(a1); o.z = f2bu(a2); o.w = f2bu(a3);
  *(ushort4*)(outp + (size_t)n*256 + lane*4) = o;
}

// ---------- MFMA bf16 GEMM: out = (A1 @ W1^T) + (A2 @ W2^T) + bias ----------
// A bf16 [M][lda], W bf16 [256][K] row-major, K % 32 == 0. Tile 128x128, 4 waves 2x2.
__global__ __launch_bounds__(256) void gemm_mfma_kernel(
    const u16* __restrict__ A1, int lda1, const u16* __restrict__ W1, int K1,
    const u16* __restrict__ A2, int lda2, const u16* __restrict__ W2, int K2,
    const float* __restrict__ bias,
    u16* __restrict__ out_bf,
    void* __restrict__ out_emb,
    u16* __restrict__ out_relu_bf,
    const int* __restrict__ flags, int M){
  __shared__ u16 Asm[128][40];   // pad 32->40: frag reads hit each bank exactly 2x (free)
  __shared__ u16 Wsm[128][40];
  int t = threadIdx.x;
  int wave = t >> 6, lane = t & 63;
  int wr = wave >> 1, wc = wave & 1;
  int m0 = blockIdx.x << 7;
  int o0 = blockIdx.y << 7;
  int lrow = t >> 1;            // staging row 0..127
  int lk8  = (t & 1) << 3;      // staging k offset 0/8 (plus +16 second load)
  int fr = lane & 15;           // fragment row/col
  int fk = (lane >> 4) << 3;    // fragment k base
  f32x4 acc[4][4] = {};

  for (int pass = 0; pass < 2; ++pass){
    const u16* A; const u16* W; int K, lda;
    if (pass == 0){ A = A1; W = W1; K = K1; lda = lda1; }
    else { if (!A2) break; A = A2; W = W2; K = K2; lda = lda2; }
    for (int k0 = 0; k0 < K; k0 += 32){
      int gm = m0 + lrow;
      int4 av0 = make_int4(0,0,0,0), av1 = av0;
      if (gm < M){
        const int4* ap = (const int4*)(A + (size_t)gm*lda + k0 + lk8);
        av0 = ap[0];
        av1 = ap[2];     // +16 elements
      }
      const int4* wp = (const int4*)(W + (size_t)(o0 + lrow)*K + k0 + lk8);
      int4 wv0 = wp[0];
      int4 wv1 = wp[2];
      *(int4*)&Asm[lrow][lk8]      = av0;
      *(int4*)&Asm[lrow][lk8+16]   = av1;
      *(int4*)&Wsm[lrow][lk8]      = wv0;
      *(int4*)&Wsm[lrow][lk8+16]   = wv1;
      __syncthreads();
      bf16x8 af[4], wf[4];
      #pragma unroll
      for (int i = 0; i < 4; i++) af[i] = *(const bf16x8*)&Asm[wr*64 + i*16 + fr][fk];
      #pragma unroll
      for (int jj = 0; jj < 4; jj++) wf[jj] = *(const bf16x8*)&Wsm[wc*64 + jj*16 + fr][fk];
      #pragma unroll
      for (int i = 0; i < 4; i++)
        #pragma unroll
        for (int jj = 0; jj < 4; jj++)
          acc[i][jj] = __builtin_amdgcn_mfma_f32_16x16x32_bf16(af[i], wf[jj], acc[i][jj], 0, 0, 0);
      __syncthreads();
    }
  }
  int isbf = flags[1];
  int fg = lane >> 4;
  #pragma unroll
  for (int i = 0; i < 4; i++){
    int rbase = m0 + wr*64 + i*16 + fg*4;
    #pragma unroll
    for (int jj = 0; jj < 4; jj++){
      int col = o0 + wc*64 + jj*16 + fr;
      float bv = bias[col];
      #pragma unroll
      for (int r = 0; r < 4; r++){
        int row = rbase + r;
        if (row < M){
          float v = acc[i][jj][r] + bv;
          size_t off = (size_t)row*256 + col;
          if (out_bf)   out_bf[off] = f2bu(v);
          if (out_emb){
            if (isbf) ((u16*)out_emb)[off] = f2bu(v);
            else      ((float*)out_emb)[off] = v;
          }
          if (out_relu_bf) out_relu_bf[off] = f2bu(fmaxf(v, 0.f));
        }
      }
    }
  }
}

// ---------- relu + layernorm (bf16 in/out) ----------
__global__ __launch_bounds__(256) void relu_ln_kernel(
    const u16* __restrict__ inb, u16* __restrict__ outb,
    const float* __restrict__ g, const float* __restrict__ b){
  __shared__ float rs[4], rs2[4];
  int n = blockIdx.x, t = threadIdx.x;
  float v = fmaxf(bu2f(inb[(size_t)n*256 + t]), 0.f);
  float s = v, s2 = v*v;
  #pragma unroll
  for (int off = 1; off < 64; off <<= 1){ s += __shfl_xor(s, off); s2 += __shfl_xor(s2, off); }
  if ((t & 63) == 0){ rs[t>>6] = s; rs2[t>>6] = s2; }
  __syncthreads();
  float S  = rs[0]+rs[1]+rs[2]+rs[3];
  float S2 = rs2[0]+rs2[1]+rs2[2]+rs2[3];
  float mu  = S * (1.f/256.f);
  float var = S2 * (1.f/256.f) - mu*mu;
  float inv = rsqrtf(var + 1e-5f);
  outb[(size_t)n*256 + t] = f2bu((v - mu) * inv * g[t] + b[t]);
}

// ---------- head: z2 = z1 @ mp2^T + b2; log_softmax ----------
__global__ __launch_bounds__(256) void head_kernel(
    const u16* __restrict__ z1, const float* __restrict__ w2, const float* __restrict__ b2,
    void* __restrict__ outbase, size_t out_off, const int* __restrict__ flags, int M){
  __shared__ float wsm[1280];
  __shared__ float bs[5];
  int t = threadIdx.x;
  for (int i = t; i < 320; i += 256){
    float4 u = ((const float4*)w2)[i];
    wsm[4*i]=u.x; wsm[4*i+1]=u.y; wsm[4*i+2]=u.z; wsm[4*i+3]=u.w;
  }
  if (t < 5) bs[t] = b2[t];
  __syncthreads();
  int n = blockIdx.x*256 + t;
  if (n >= M) return;
  const u16* zp = z1 + (size_t)n*256;
  float acc[5];
  #pragma unroll
  for (int o = 0; o < 5; o++) acc[o] = bs[o];
  for (int k = 0; k < 256; k += 4){
    ushort4 zu = *(const ushort4*)(zp + k);
    float z0 = bu2f(zu.x), z1f = bu2f(zu.y), z2 = bu2f(zu.z), z3 = bu2f(zu.w);
    #pragma unroll
    for (int o = 0; o < 5; o++){
      const float* w = wsm + o*256 + k;
      acc[o] += z0*w[0] + z1f*w[1] + z2*w[2] + z3*w[3];
    }
  }
  float mx = acc[0];
  #pragma unroll
  for (int o = 1; o < 5; o++) mx = fmaxf(mx, acc[o]);
  float se = 0.f;
  #pragma unroll
  for (int o = 0; o < 5; o++) se += expf(acc[o] - mx);
  float lse = mx + logf(se);
  int isbf = flags[1];
  if (isbf){
    u16* op = (u16*)outbase + out_off + (size_t)n*5;
    #pragma unroll
    for (int o = 0; o < 5; o++) op[o] = f2bu(acc[o] - lse);
  } else {
    float* op = (float*)outbase + out_off + (size_t)n*5;
    #pragma unroll
    for (int o = 0; o < 5; o++) op[o] = acc[o] - lse;
  }
}

extern "C" void kernel_launch(void* const* d_in, const int* in_sizes, int n_in,
                              void* d_out, int out_size, void* d_ws, size_t ws_size,
                              hipStream_t stream){
  (void)in_sizes; (void)n_in; (void)out_size; (void)ws_size;
  const void* x    = d_in[0];
  const void* bd   = d_in[1];
  const void* eraw = d_in[2];

  char* ws = (char*)d_ws;
  const size_t OFF_H0 = 0;                                    // bf16 [NN][672]
  const size_t OFF_A  = OFF_H0 + (size_t)NN*672*2;            // bf16 [NN][256]
  const size_t OFF_B  = OFF_A  + (size_t)NN*256*2;
  const size_t OFF_C  = OFF_B  + (size_t)NN*256*2;
  const size_t OFF_DEG= OFF_C  + (size_t)NN*256*2;
  const size_t OFF_INV= OFF_DEG + (size_t)NN*4;
  const size_t OFF_EDG= OFF_INV + (size_t)NN*4;
  const size_t OFF_RP = OFF_EDG + (size_t)2*EE*4;
  const size_t OFF_CUR= OFF_RP  + (size_t)(NN+16)*4;
  const size_t OFF_EBU= OFF_CUR + (size_t)NN*4;
  const size_t OFF_FLG= OFF_EBU + (size_t)EE*4;
  const size_t OFF_PRM= OFF_FLG + 256;

  u16*   h0   = (u16*)(ws + OFF_H0);
  u16*   bufA = (u16*)(ws + OFF_A);
  u16*   bufB = (u16*)(ws + OFF_B);
  u16*   bufC = (u16*)(ws + OFF_C);
  int*   degI = (int*)(ws + OFF_DEG);
  float* invd = (float*)(ws + OFF_INV);
  int*   edg  = (int*)(ws + OFF_EDG);
  int*   rowp = (int*)(ws + OFF_RP);
  int*   curs = (int*)(ws + OFF_CUR);
  int*   ebuc = (int*)(ws + OFF_EBU);
  int*   flg  = (int*)(ws + OFF_FLG);
  char*  prm  = ws + OFF_PRM;
  const int* esrc = edg;
  const int* edst = edg + EE;

  // canon entries: {rows, srcK, dstK, tobf}
  static const int crows[15] = {1,1,256,1,256,1,1,1,1,1,1,1,1,1,1};
  static const int csk[15]   = {576,8,652,256,652,256,196608,768,196608,512,512,65536,256,1280,5};
  static const int cdk[15]   = {576,8,672,256,672,256,196608,768,196608,512,512,65536,256,1280,5};
  static const int ctobf[15] = {0,0,1,0,1,0,1,0,1,0,0,1,0,0,0};
  CanonTab tab;
  size_t po = 0;
  void* dsts[15];
  for (int i = 0; i < 15; i++){
    tab.src[i] = d_in[3+i];
    tab.rows[i] = crows[i]; tab.sk[i] = csk[i]; tab.dk[i] = cdk[i]; tab.tobf[i] = ctobf[i];
    dsts[i] = prm + po;
    tab.dst[i] = dsts[i];
    size_t bytes = (size_t)crows[i]*cdk[i] * (ctobf[i] ? 2 : 4);
    po += (bytes + 63) & ~(size_t)63;
  }
  const float* c_cw  = (const float*)dsts[0];
  const float* c_cb  = (const float*)dsts[1];
  const u16*   c_lw  = (const u16*)dsts[2];
  const float* c_lb  = (const float*)dsts[3];
  const u16*   c_lsw = (const u16*)dsts[4];
  const float* c_lsb = (const float*)dsts[5];
  const u16*   c_slw = (const u16*)dsts[6];
  const float* c_slb = (const float*)dsts[7];
  const u16*   c_srw = (const u16*)dsts[8];
  const float* c_lng = (const float*)dsts[9];
  const float* c_lnb = (const float*)dsts[10];
  const u16*   c_m1w = (const u16*)dsts[11];
  const float* c_m1b = (const float*)dsts[12];
  const float* c_m2w = (const float*)dsts[13];
  const float* c_m2b = (const float*)dsts[14];

  hipMemsetAsync(degI, 0, (size_t)NN*4, stream);
  sniff_kernel<<<1, 256, 0, stream>>>((const int*)eraw, (const u16*)x, flg);
  {
    dim3 cgrid(96, 15);   // 2048 elements per block; covers max param (196608)
    canon_params_kernel<<<cgrid, 256, 0, stream>>>(tab, flg);
  }
  convert_edges_kernel<<<(2*EE + 255)/256, 256, 0, stream>>>(eraw, edg, flg, 2*EE);
  conv_relu_kernel<<<NN, 256, 0, stream>>>(x, bd, c_cw, c_cb, flg, h0);
  deg_kernel<<<(EE + 255)/256, 256, 0, stream>>>(edst, degI, EE);
  invdeg_kernel<<<(NN + 255)/256, 256, 0, stream>>>(degI, invd, NN);
  scan_kernel<<<1, 1024, 0, stream>>>(degI, rowp, curs, NN);
  bucket_kernel<<<(EE + 255)/256, 256, 0, stream>>>(esrc, edst, curs, ebuc, EE);

  dim3 ggrid((NN + 127)/128, 2);
  const int agrid = (NN + 3)/4;
  // layer 0: self_x -> bufA, neigh -> bufB, then bufA[n] += sum_in bufB[src]
  gemm_mfma_kernel<<<ggrid, 256, 0, stream>>>(h0, 672, c_lsw, 672,
      nullptr, 0, nullptr, 0, c_lsb, bufA, nullptr, nullptr, flg, NN);
  gemm_mfma_kernel<<<ggrid, 256, 0, stream>>>(h0, 672, c_lw, 672,
      nullptr, 0, nullptr, 0, c_lb, bufB, nullptr, nullptr, flg, NN);
  gather_agg_kernel<<<agrid, 256, 0, stream>>>(bufB, bufA, nullptr, bufA, rowp, ebuc);

  // SAGE layers: h in bufA; mean-agg (pre-scaled by invd) in bufC; gemm -> bufB
  for (int i = 0; i < 3; i++){
    gather_agg_kernel<<<agrid, 256, 0, stream>>>(bufA, nullptr, invd, bufC, rowp, ebuc);
    const u16*   L  = c_slw + (size_t)i*256*256;
    const float* Lb = c_slb + (size_t)i*256;
    const u16*   R  = c_srw + (size_t)i*256*256;
    if (i < 2){
      gemm_mfma_kernel<<<ggrid, 256, 0, stream>>>(bufC, 256, L, 256,
          bufA, 256, R, 256, Lb, bufB, nullptr, nullptr, flg, NN);
      relu_ln_kernel<<<NN, 256, 0, stream>>>(bufB, bufA,
          c_lng + (size_t)i*256, c_lnb + (size_t)i*256);
    } else {
      gemm_mfma_kernel<<<ggrid, 256, 0, stream>>>(bufC, 256, L, 256,
          bufA, 256, R, 256, Lb, nullptr, d_out, bufB, flg, NN);
    }
  }
  gemm_mfma_kernel<<<ggrid, 256, 0, stream>>>(bufB, 256, c_m1w, 256,
      nullptr, 0, nullptr, 0, c_m1b, bufC, nullptr, nullptr, flg, NN);
  head_kernel<<<(NN + 255)/256, 256, 0, stream>>>(bufC, c_m2w, c_m2b,
      d_out, (size_t)NN*256, flg, NN);
}

// Round 6
// 899.751 us; speedup vs baseline: 14.0390x; 1.1296x over previous
//
#include <hip/hip_runtime.h>
#include <hip/hip_bf16.h>
#include <stdint.h>

#define NN 50000
#define EE 800000

typedef unsigned short u16;
typedef __attribute__((ext_vector_type(4))) float f32x4;
typedef __attribute__((ext_vector_type(8))) short bf16x8;

__device__ __forceinline__ float bu2f(u16 u){ return __uint_as_float(((unsigned)u)<<16); }
__device__ __forceinline__ u16 f2bu(float f){
  unsigned u = __float_as_uint(f);
  u += 0x7fffu + ((u>>16)&1u);      // round-to-nearest-even
  return (u16)(u>>16);
}

// ---------- sniff: flags[0] = edges are int64; flags[1] = float inputs are bf16 ----------
__global__ void sniff_kernel(const int* __restrict__ e, const u16* __restrict__ xu,
                             int* __restrict__ flags){
  __shared__ int nz, cnt;
  int t = threadIdx.x;
  if (t == 0){ nz = 0; cnt = 0; }
  __syncthreads();
  if (e[2*t + 1] != 0) atomicOr(&nz, 1);
  u16 u = xu[2*t];
  int ef = (u >> 7) & 0xFF;
  int ok = (u == 0) || (ef >= 118 && ef <= 132);
  atomicAdd(&cnt, ok);
  __syncthreads();
  if (t == 0){ flags[0] = (nz == 0) ? 1 : 0; flags[1] = (cnt >= 200) ? 1 : 0; }
}

__global__ void convert_edges_kernel(const void* __restrict__ ep, int* __restrict__ outp,
                                     const int* __restrict__ flags, int total){
  int i = blockIdx.x*256 + threadIdx.x;
  if (i >= total) return;
  if (flags[0]) outp[i] = (int)((const long long*)ep)[i];
  else          outp[i] = ((const int*)ep)[i];
}

// ---------- canonicalize params: optional K-pad, to bf16 or fp32 ----------
struct CanonTab {
  const void* src[15];
  void*       dst[15];
  int rows[15];
  int sk[15];
  int dk[15];
  int tobf[15];
};

__global__ __launch_bounds__(256) void canon_params_kernel(CanonTab tab, const int* __restrict__ flags){
  int a = blockIdx.y;
  int isbf = flags[1];
  int rows = tab.rows[a], sk = tab.sk[a], dk = tab.dk[a], tobf = tab.tobf[a];
  int n = rows * dk;
  int base = (blockIdx.x*256 + threadIdx.x) * 8;
  if (base >= n) return;
  #pragma unroll
  for (int uu = 0; uu < 8; uu++){
    int i = base + uu;
    if (i >= n) break;
    int r = i / dk, c = i - r*dk;
    float v = 0.f;
    if (c < sk){
      size_t si = (size_t)r*sk + c;
      v = isbf ? bu2f(((const u16*)tab.src[a])[si]) : ((const float*)tab.src[a])[si];
    }
    if (tobf) ((u16*)tab.dst[a])[i] = f2bu(v);
    else      ((float*)tab.dst[a])[i] = v;
  }
}

// ---------- conv3x3 VALID + bias + concat(bd) + relu -> h0 bf16 [NN][704] (cols 652..703 zero) ----
// t<216: thread owns (co = t&7, rowid = t>>3): oi = rowid/3, oj base = (rowid%3)*3.
// Weights for co kept in 72 VGPRs (read once); x via 5-wide LDS window -> 9 FMA per window.
__global__ __launch_bounds__(256) void conv_relu_kernel(
    const void* __restrict__ xraw, const void* __restrict__ bdraw,
    const float* __restrict__ cw, const float* __restrict__ cb,
    const int* __restrict__ flags, u16* __restrict__ h0){
  __shared__ float xs[968];    // 8*121
  __shared__ float wsm[576];   // 8*8*9
  __shared__ float bs[8];
  int n = blockIdx.x, t = threadIdx.x;
  int isbf = flags[1];
  if (isbf){
    const ushort4* xp = (const ushort4*)((const u16*)xraw + (size_t)n*968);
    if (t < 242){ ushort4 u = xp[t]; xs[4*t]=bu2f(u.x); xs[4*t+1]=bu2f(u.y); xs[4*t+2]=bu2f(u.z); xs[4*t+3]=bu2f(u.w); }
  } else {
    const float4* xp = (const float4*)((const float*)xraw + (size_t)n*968);
    if (t < 242){ float4 u = xp[t]; xs[4*t]=u.x; xs[4*t+1]=u.y; xs[4*t+2]=u.z; xs[4*t+3]=u.w; }
  }
  if (t < 144){ float4 u = ((const float4*)cw)[t]; wsm[4*t]=u.x; wsm[4*t+1]=u.y; wsm[4*t+2]=u.z; wsm[4*t+3]=u.w; }
  if (t < 8) bs[t] = cb[t];
  __syncthreads();
  u16* outr = h0 + (size_t)n*704;
  if (t < 216){
    int co = t & 7;
    int rowid = t >> 3;        // 0..26
    int oi = rowid / 3;        // 0..8
    int og = rowid - oi*3;     // 0..2
    float wreg[72];
    #pragma unroll
    for (int q = 0; q < 72; q++) wreg[q] = wsm[co*72 + q];
    float a0 = bs[co], a1 = a0, a2 = a0;
    #pragma unroll
    for (int ci = 0; ci < 8; ci++){
      #pragma unroll
      for (int ki = 0; ki < 3; ki++){
        const float* xb = xs + ci*121 + (oi+ki)*11 + og*3;
        float x0=xb[0], x1=xb[1], x2=xb[2], x3=xb[3], x4=xb[4];
        float w0=wreg[ci*9+ki*3+0], w1=wreg[ci*9+ki*3+1], w2=wreg[ci*9+ki*3+2];
        a0 += x0*w0 + x1*w1 + x2*w2;
        a1 += x1*w0 + x2*w1 + x3*w2;
        a2 += x2*w0 + x3*w1 + x4*w2;
      }
    }
    int colbase = co*81 + oi*9 + og*3;
    outr[colbase+0] = f2bu(fmaxf(a0, 0.f));
    outr[colbase+1] = f2bu(fmaxf(a1, 0.f));
    outr[colbase+2] = f2bu(fmaxf(a2, 0.f));
  } else if (t < 220){
    int jj = t - 216;
    float v = isbf ? bu2f(((const u16*)bdraw)[(size_t)n*4 + jj]) : ((const float*)bdraw)[(size_t)n*4 + jj];
    outr[648 + jj] = f2bu(fmaxf(v, 0.f));
  } else {
    for (int c = 652 + (t - 220); c < 704; c += 36) outr[c] = 0;
  }
}

// ---------- degree ----------
__global__ void deg_kernel(const int* __restrict__ dst, int* __restrict__ degI, int E){
  int e = blockIdx.x*256 + threadIdx.x;
  if (e < E) atomicAdd(&degI[dst[e]], 1);
}
__global__ void invdeg_kernel(const int* __restrict__ degI, float* __restrict__ inv, int n){
  int i = blockIdx.x*256 + threadIdx.x;
  if (i < n){ int d = degI[i]; inv[i] = 1.0f / (float)(d > 1 ? d : 1); }
}

// ---------- exclusive scan of degI -> rowptr (single block, 1024 threads) ----------
__global__ __launch_bounds__(1024) void scan_kernel(const int* __restrict__ degI,
                                                    int* __restrict__ rowptr,
                                                    int* __restrict__ cursor, int n){
  __shared__ int warp_sums[16];
  __shared__ int carry;
  int t = threadIdx.x;
  if (t == 0) carry = 0;
  __syncthreads();
  for (int base = 0; base < n; base += 1024){
    int i = base + t;
    int v = (i < n) ? degI[i] : 0;
    int s = v;
    #pragma unroll
    for (int off = 1; off < 64; off <<= 1){ int u = __shfl_up(s, off); if ((t & 63) >= off) s += u; }
    if ((t & 63) == 63) warp_sums[t >> 6] = s;
    __syncthreads();
    if (t < 16){
      int wsv = warp_sums[t];
      #pragma unroll
      for (int off = 1; off < 16; off <<= 1){ int u = __shfl_up(wsv, off); if (t >= off) wsv += u; }
      warp_sums[t] = wsv;
    }
    __syncthreads();
    int block_off = (t >= 64) ? warp_sums[(t >> 6) - 1] : 0;
    int excl = carry + block_off + s - v;
    if (i < n){ rowptr[i] = excl; cursor[i] = excl; }
    int total = warp_sums[15];
    __syncthreads();
    if (t == 0) carry += total;
    __syncthreads();
  }
  if (t == 0) rowptr[n] = carry;
}

// ---------- bucket fill: ebuc[cursor[dst]++] = src ----------
__global__ void bucket_kernel(const int* __restrict__ esrc, const int* __restrict__ edst,
                              int* __restrict__ cursor, int* __restrict__ ebuc, int E){
  int e = blockIdx.x*256 + threadIdx.x;
  if (e < E){ int pos = atomicAdd(&cursor[edst[e]], 1); ebuc[pos] = esrc[e]; }
}

// ---------- gather-aggregate (bf16): out[n] = (addbase?addbase[n]:0) + scale[n]*sum src[nbr] ----
__global__ __launch_bounds__(256) void gather_agg_kernel(
    const u16* __restrict__ src_feat, const u16* __restrict__ addbase,
    const float* __restrict__ scale, u16* __restrict__ outp,
    const int* __restrict__ rowptr, const int* __restrict__ ebuc){
  int wid = threadIdx.x >> 6, lane = threadIdx.x & 63;
  int n = blockIdx.x*4 + wid;
  if (n >= NN) return;
  int beg = rowptr[n], end = rowptr[n+1];
  float a0=0.f,a1=0.f,a2=0.f,a3=0.f;
  float b0=0.f,b1=0.f,b2=0.f,b3=0.f;
  int j = beg;
  for (; j + 1 < end; j += 2){
    int s0 = ebuc[j], s1 = ebuc[j+1];
    ushort4 v0 = *(const ushort4*)(src_feat + (size_t)s0*256 + lane*4);
    ushort4 v1 = *(const ushort4*)(src_feat + (size_t)s1*256 + lane*4);
    a0 += bu2f(v0.x); a1 += bu2f(v0.y); a2 += bu2f(v0.z); a3 += bu2f(v0.w);
    b0 += bu2f(v1.x); b1 += bu2f(v1.y); b2 += bu2f(v1.z); b3 += bu2f(v1.w);
  }
  if (j < end){
    ushort4 v0 = *(const ushort4*)(src_feat + (size_t)ebuc[j]*256 + lane*4);
    a0 += bu2f(v0.x); a1 += bu2f(v0.y); a2 += bu2f(v0.z); a3 += bu2f(v0.w);
  }
  float sc = scale ? scale[n] : 1.f;
  a0 = (a0+b0)*sc; a1 = (a1+b1)*sc; a2 = (a2+b2)*sc; a3 = (a3+b3)*sc;
  if (addbase){
    ushort4 b = *(const ushort4*)(addbase + (size_t)n*256 + lane*4);
    a0 += bu2f(b.x); a1 += bu2f(b.y); a2 += bu2f(b.z); a3 += bu2f(b.w);
  }
  ushort4 o; o.x = f2bu(a0); o.y = f2bu(a1); o.z = f2bu(a2); o.w = f2bu(a3);
  *(ushort4*)(outp + (size_t)n*256 + lane*4) = o;
}

// ---------- MFMA bf16 GEMM: out = (A1 @ W1^T) + (A2 @ W2^T) + bias ----------
// A bf16 [M][lda], W bf16 [256][K] row-major, K % 64 == 0. Tile 128x128, BK=64, 4 waves 2x2.
__global__ __launch_bounds__(256) void gemm_mfma_kernel(
    const u16* __restrict__ A1, int lda1, const u16* __restrict__ W1, int K1,
    const u16* __restrict__ A2, int lda2, const u16* __restrict__ W2, int K2,
    const float* __restrict__ bias,
    u16* __restrict__ out_bf,
    void* __restrict__ out_emb,
    u16* __restrict__ out_relu_bf,
    const int* __restrict__ flags, int M){
  __shared__ u16 Asm[128][72];   // stride 36 words: rows alias banks 2-way (free)
  __shared__ u16 Wsm[128][72];
  int t = threadIdx.x;
  int wave = t >> 6, lane = t & 63;
  int wr = wave >> 1, wc = wave & 1;
  int m0 = blockIdx.x << 7;
  int o0 = blockIdx.y << 7;
  int lrow = t >> 1;            // staging row 0..127
  int lk8  = (t & 1) << 3;      // staging k offset 0/8 (+16/+32/+48 more loads)
  int fr = lane & 15;
  int fkb = (lane >> 4) << 3;   // 0,8,16,24
  f32x4 acc[4][4] = {};

  for (int pass = 0; pass < 2; ++pass){
    const u16* A; const u16* W; int K, lda;
    if (pass == 0){ A = A1; W = W1; K = K1; lda = lda1; }
    else { if (!A2) break; A = A2; W = W2; K = K2; lda = lda2; }
    for (int k0 = 0; k0 < K; k0 += 64){
      int gm = m0 + lrow;
      int4 av0 = make_int4(0,0,0,0), av1 = av0, av2 = av0, av3 = av0;
      if (gm < M){
        const int4* ap = (const int4*)(A + (size_t)gm*lda + k0 + lk8);
        av0 = ap[0]; av1 = ap[2]; av2 = ap[4]; av3 = ap[6];
      }
      const int4* wp = (const int4*)(W + (size_t)(o0 + lrow)*K + k0 + lk8);
      int4 wv0 = wp[0], wv1 = wp[2], wv2 = wp[4], wv3 = wp[6];
      *(int4*)&Asm[lrow][lk8]      = av0;
      *(int4*)&Asm[lrow][lk8+16]   = av1;
      *(int4*)&Asm[lrow][lk8+32]   = av2;
      *(int4*)&Asm[lrow][lk8+48]   = av3;
      *(int4*)&Wsm[lrow][lk8]      = wv0;
      *(int4*)&Wsm[lrow][lk8+16]   = wv1;
      *(int4*)&Wsm[lrow][lk8+32]   = wv2;
      *(int4*)&Wsm[lrow][lk8+48]   = wv3;
      __syncthreads();
      #pragma unroll
      for (int kk = 0; kk < 2; kk++){
        int fk = kk*32 + fkb;
        bf16x8 af[4], wf[4];
        #pragma unroll
        for (int i = 0; i < 4; i++) af[i] = *(const bf16x8*)&Asm[wr*64 + i*16 + fr][fk];
        #pragma unroll
        for (int jj = 0; jj < 4; jj++) wf[jj] = *(const bf16x8*)&Wsm[wc*64 + jj*16 + fr][fk];
        #pragma unroll
        for (int i = 0; i < 4; i++)
          #pragma unroll
          for (int jj = 0; jj < 4; jj++)
            acc[i][jj] = __builtin_amdgcn_mfma_f32_16x16x32_bf16(af[i], wf[jj], acc[i][jj], 0, 0, 0);
      }
      __syncthreads();
    }
  }
  int isbf = flags[1];
  int fg = lane >> 4;
  #pragma unroll
  for (int i = 0; i < 4; i++){
    int rbase = m0 + wr*64 + i*16 + fg*4;
    #pragma unroll
    for (int jj = 0; jj < 4; jj++){
      int col = o0 + wc*64 + jj*16 + fr;
      float bv = bias[col];
      #pragma unroll
      for (int r = 0; r < 4; r++){
        int row = rbase + r;
        if (row < M){
          float v = acc[i][jj][r] + bv;
          size_t off = (size_t)row*256 + col;
          if (out_bf)   out_bf[off] = f2bu(v);
          if (out_emb){
            if (isbf) ((u16*)out_emb)[off] = f2bu(v);
            else      ((float*)out_emb)[off] = v;
          }
          if (out_relu_bf) out_relu_bf[off] = f2bu(fmaxf(v, 0.f));
        }
      }
    }
  }
}

// ---------- relu + layernorm (bf16 in/out) ----------
__global__ __launch_bounds__(256) void relu_ln_kernel(
    const u16* __restrict__ inb, u16* __restrict__ outb,
    const float* __restrict__ g, const float* __restrict__ b){
  __shared__ float rs[4], rs2[4];
  int n = blockIdx.x, t = threadIdx.x;
  float v = fmaxf(bu2f(inb[(size_t)n*256 + t]), 0.f);
  float s = v, s2 = v*v;
  #pragma unroll
  for (int off = 1; off < 64; off <<= 1){ s += __shfl_xor(s, off); s2 += __shfl_xor(s2, off); }
  if ((t & 63) == 0){ rs[t>>6] = s; rs2[t>>6] = s2; }
  __syncthreads();
  float S  = rs[0]+rs[1]+rs[2]+rs[3];
  float S2 = rs2[0]+rs2[1]+rs2[2]+rs2[3];
  float mu  = S * (1.f/256.f);
  float var = S2 * (1.f/256.f) - mu*mu;
  float inv = rsqrtf(var + 1e-5f);
  outb[(size_t)n*256 + t] = f2bu((v - mu) * inv * g[t] + b[t]);
}

// ---------- head: z2 = z1 @ mp2^T + b2; log_softmax ----------
__global__ __launch_bounds__(256) void head_kernel(
    const u16* __restrict__ z1, const float* __restrict__ w2, const float* __restrict__ b2,
    void* __restrict__ outbase, size_t out_off, const int* __restrict__ flags, int M){
  __shared__ float wsm[1280];
  __shared__ float bs[5];
  int t = threadIdx.x;
  for (int i = t; i < 320; i += 256){
    float4 u = ((const float4*)w2)[i];
    wsm[4*i]=u.x; wsm[4*i+1]=u.y; wsm[4*i+2]=u.z; wsm[4*i+3]=u.w;
  }
  if (t < 5) bs[t] = b2[t];
  __syncthreads();
  int n = blockIdx.x*256 + t;
  if (n >= M) return;
  const u16* zp = z1 + (size_t)n*256;
  float acc[5];
  #pragma unroll
  for (int o = 0; o < 5; o++) acc[o] = bs[o];
  for (int k = 0; k < 256; k += 4){
    ushort4 zu = *(const ushort4*)(zp + k);
    float z0 = bu2f(zu.x), z1f = bu2f(zu.y), z2 = bu2f(zu.z), z3 = bu2f(zu.w);
    #pragma unroll
    for (int o = 0; o < 5; o++){
      const float* w = wsm + o*256 + k;
      acc[o] += z0*w[0] + z1f*w[1] + z2*w[2] + z3*w[3];
    }
  }
  float mx = acc[0];
  #pragma unroll
  for (int o = 1; o < 5; o++) mx = fmaxf(mx, acc[o]);
  float se = 0.f;
  #pragma unroll
  for (int o = 0; o < 5; o++) se += expf(acc[o] - mx);
  float lse = mx + logf(se);
  int isbf = flags[1];
  if (isbf){
    u16* op = (u16*)outbase + out_off + (size_t)n*5;
    #pragma unroll
    for (int o = 0; o < 5; o++) op[o] = f2bu(acc[o] - lse);
  } else {
    float* op = (float*)outbase + out_off + (size_t)n*5;
    #pragma unroll
    for (int o = 0; o < 5; o++) op[o] = acc[o] - lse;
  }
}

extern "C" void kernel_launch(void* const* d_in, const int* in_sizes, int n_in,
                              void* d_out, int out_size, void* d_ws, size_t ws_size,
                              hipStream_t stream){
  (void)in_sizes; (void)n_in; (void)out_size; (void)ws_size;
  const void* x    = d_in[0];
  const void* bd   = d_in[1];
  const void* eraw = d_in[2];

  char* ws = (char*)d_ws;
  const size_t OFF_H0 = 0;                                    // bf16 [NN][704]
  const size_t OFF_A  = OFF_H0 + (size_t)NN*704*2;            // bf16 [NN][256]
  const size_t OFF_B  = OFF_A  + (size_t)NN*256*2;
  const size_t OFF_C  = OFF_B  + (size_t)NN*256*2;
  const size_t OFF_DEG= OFF_C  + (size_t)NN*256*2;
  const size_t OFF_INV= OFF_DEG + (size_t)NN*4;
  const size_t OFF_EDG= OFF_INV + (size_t)NN*4;
  const size_t OFF_RP = OFF_EDG + (size_t)2*EE*4;
  const size_t OFF_CUR= OFF_RP  + (size_t)(NN+16)*4;
  const size_t OFF_EBU= OFF_CUR + (size_t)NN*4;
  const size_t OFF_FLG= OFF_EBU + (size_t)EE*4;
  const size_t OFF_PRM= OFF_FLG + 256;

  u16*   h0   = (u16*)(ws + OFF_H0);
  u16*   bufA = (u16*)(ws + OFF_A);
  u16*   bufB = (u16*)(ws + OFF_B);
  u16*   bufC = (u16*)(ws + OFF_C);
  int*   degI = (int*)(ws + OFF_DEG);
  float* invd = (float*)(ws + OFF_INV);
  int*   edg  = (int*)(ws + OFF_EDG);
  int*   rowp = (int*)(ws + OFF_RP);
  int*   curs = (int*)(ws + OFF_CUR);
  int*   ebuc = (int*)(ws + OFF_EBU);
  int*   flg  = (int*)(ws + OFF_FLG);
  char*  prm  = ws + OFF_PRM;
  const int* esrc = edg;
  const int* edst = edg + EE;

  // canon entries: {rows, srcK, dstK (pad to mult of 64 for GEMM K), tobf}
  static const int crows[15] = {1,1,256,1,256,1,1,1,1,1,1,1,1,1,1};
  static const int csk[15]   = {576,8,652,256,652,256,196608,768,196608,512,512,65536,256,1280,5};
  static const int cdk[15]   = {576,8,704,256,704,256,196608,768,196608,512,512,65536,256,1280,5};
  static const int ctobf[15] = {0,0,1,0,1,0,1,0,1,0,0,1,0,0,0};
  CanonTab tab;
  size_t po = 0;
  void* dsts[15];
  for (int i = 0; i < 15; i++){
    tab.src[i] = d_in[3+i];
    tab.rows[i] = crows[i]; tab.sk[i] = csk[i]; tab.dk[i] = cdk[i]; tab.tobf[i] = ctobf[i];
    dsts[i] = prm + po;
    tab.dst[i] = dsts[i];
    size_t bytes = (size_t)crows[i]*cdk[i] * (ctobf[i] ? 2 : 4);
    po += (bytes + 63) & ~(size_t)63;
  }
  const float* c_cw  = (const float*)dsts[0];
  const float* c_cb  = (const float*)dsts[1];
  const u16*   c_lw  = (const u16*)dsts[2];
  const float* c_lb  = (const float*)dsts[3];
  const u16*   c_lsw = (const u16*)dsts[4];
  const float* c_lsb = (const float*)dsts[5];
  const u16*   c_slw = (const u16*)dsts[6];
  const float* c_slb = (const float*)dsts[7];
  const u16*   c_srw = (const u16*)dsts[8];
  const float* c_lng = (const float*)dsts[9];
  const float* c_lnb = (const float*)dsts[10];
  const u16*   c_m1w = (const u16*)dsts[11];
  const float* c_m1b = (const float*)dsts[12];
  const float* c_m2w = (const float*)dsts[13];
  const float* c_m2b = (const float*)dsts[14];

  hipMemsetAsync(degI, 0, (size_t)NN*4, stream);
  sniff_kernel<<<1, 256, 0, stream>>>((const int*)eraw, (const u16*)x, flg);
  {
    dim3 cgrid(96, 15);
    canon_params_kernel<<<cgrid, 256, 0, stream>>>(tab, flg);
  }
  convert_edges_kernel<<<(2*EE + 255)/256, 256, 0, stream>>>(eraw, edg, flg, 2*EE);
  conv_relu_kernel<<<NN, 256, 0, stream>>>(x, bd, c_cw, c_cb, flg, h0);
  deg_kernel<<<(EE + 255)/256, 256, 0, stream>>>(edst, degI, EE);
  invdeg_kernel<<<(NN + 255)/256, 256, 0, stream>>>(degI, invd, NN);
  scan_kernel<<<1, 1024, 0, stream>>>(degI, rowp, curs, NN);
  bucket_kernel<<<(EE + 255)/256, 256, 0, stream>>>(esrc, edst, curs, ebuc, EE);

  dim3 ggrid((NN + 127)/128, 2);
  const int agrid = (NN + 3)/4;
  // layer 0: self_x -> bufA, neigh -> bufB, then bufA[n] += sum_in bufB[src]
  gemm_mfma_kernel<<<ggrid, 256, 0, stream>>>(h0, 704, c_lsw, 704,
      nullptr, 0, nullptr, 0, c_lsb, bufA, nullptr, nullptr, flg, NN);
  gemm_mfma_kernel<<<ggrid, 256, 0, stream>>>(h0, 704, c_lw, 704,
      nullptr, 0, nullptr, 0, c_lb, bufB, nullptr, nullptr, flg, NN);
  gather_agg_kernel<<<agrid, 256, 0, stream>>>(bufB, bufA, nullptr, bufA, rowp, ebuc);

  // SAGE layers: h in bufA; mean-agg (pre-scaled by invd) in bufC; gemm -> bufB
  for (int i = 0; i < 3; i++){
    gather_agg_kernel<<<agrid, 256, 0, stream>>>(bufA, nullptr, invd, bufC, rowp, ebuc);
    const u16*   L  = c_slw + (size_t)i*256*256;
    const float* Lb = c_slb + (size_t)i*256;
    const u16*   R  = c_srw + (size_t)i*256*256;
    if (i < 2){
      gemm_mfma_kernel<<<ggrid, 256, 0, stream>>>(bufC, 256, L, 256,
          bufA, 256, R, 256, Lb, bufB, nullptr, nullptr, flg, NN);
      relu_ln_kernel<<<NN, 256, 0, stream>>>(bufB, bufA,
          c_lng + (size_t)i*256, c_lnb + (size_t)i*256);
    } else {
      gemm_mfma_kernel<<<ggrid, 256, 0, stream>>>(bufC, 256, L, 256,
          bufA, 256, R, 256, Lb, nullptr, d_out, bufB, flg, NN);
    }
  }
  gemm_mfma_kernel<<<ggrid, 256, 0, stream>>>(bufB, 256, c_m1w, 256,
      nullptr, 0, nullptr, 0, c_m1b, bufC, nullptr, nullptr, flg, NN);
  head_kernel<<<(NN + 255)/256, 256, 0, stream>>>(bufC, c_m2w, c_m2b,
      d_out, (size_t)NN*256, flg, NN);
}

// Round 7
// 877.586 us; speedup vs baseline: 14.3936x; 1.0253x over previous
//
#include <hip/hip_runtime.h>
#include <hip/hip_bf16.h>
#include <stdint.h>

#define NN 50000
#define EE 800000

typedef unsigned short u16;
typedef __attribute__((ext_vector_type(4))) float f32x4;
typedef __attribute__((ext_vector_type(8))) short bf16x8;

__device__ __forceinline__ float bu2f(u16 u){ return __uint_as_float(((unsigned)u)<<16); }
__device__ __forceinline__ u16 f2bu(float f){
  unsigned u = __float_as_uint(f);
  u += 0x7fffu + ((u>>16)&1u);      // round-to-nearest-even
  return (u16)(u>>16);
}
__device__ __forceinline__ float lo16f(unsigned u){ return __uint_as_float(u << 16); }
__device__ __forceinline__ float hi16f(unsigned u){ return __uint_as_float(u & 0xffff0000u); }

// ---------- sniff: flags[0] = edges are int64; flags[1] = float inputs are bf16 ----------
__global__ void sniff_kernel(const int* __restrict__ e, const u16* __restrict__ xu,
                             int* __restrict__ flags){
  __shared__ int nz, cnt;
  int t = threadIdx.x;
  if (t == 0){ nz = 0; cnt = 0; }
  __syncthreads();
  if (e[2*t + 1] != 0) atomicOr(&nz, 1);
  u16 u = xu[2*t];
  int ef = (u >> 7) & 0xFF;
  int ok = (u == 0) || (ef >= 118 && ef <= 132);
  atomicAdd(&cnt, ok);
  __syncthreads();
  if (t == 0){ flags[0] = (nz == 0) ? 1 : 0; flags[1] = (cnt >= 200) ? 1 : 0; }
}

__global__ void convert_edges_kernel(const void* __restrict__ ep, int* __restrict__ outp,
                                     const int* __restrict__ flags, int total){
  int i = blockIdx.x*256 + threadIdx.x;
  if (i >= total) return;
  if (flags[0]) outp[i] = (int)((const long long*)ep)[i];
  else          outp[i] = ((const int*)ep)[i];
}

// ---------- canonicalize params: optional K-pad, to bf16 or fp32 ----------
struct CanonTab {
  const void* src[15];
  void*       dst[15];
  int rows[15];
  int sk[15];
  int dk[15];
  int tobf[15];
};

__global__ __launch_bounds__(256) void canon_params_kernel(CanonTab tab, const int* __restrict__ flags){
  int a = blockIdx.y;
  int isbf = flags[1];
  int rows = tab.rows[a], sk = tab.sk[a], dk = tab.dk[a], tobf = tab.tobf[a];
  int n = rows * dk;
  int base = (blockIdx.x*256 + threadIdx.x) * 8;
  if (base >= n) return;
  #pragma unroll
  for (int uu = 0; uu < 8; uu++){
    int i = base + uu;
    if (i >= n) break;
    int r = i / dk, c = i - r*dk;
    float v = 0.f;
    if (c < sk){
      size_t si = (size_t)r*sk + c;
      v = isbf ? bu2f(((const u16*)tab.src[a])[si]) : ((const float*)tab.src[a])[si];
    }
    if (tobf) ((u16*)tab.dst[a])[i] = f2bu(v);
    else      ((float*)tab.dst[a])[i] = v;
  }
}

// ---------- conv3x3 VALID + bias + concat(bd) + relu -> h0 bf16 [NN][704] (cols 652..703 zero) ----
__global__ __launch_bounds__(256) void conv_relu_kernel(
    const void* __restrict__ xraw, const void* __restrict__ bdraw,
    const float* __restrict__ cw, const float* __restrict__ cb,
    const int* __restrict__ flags, u16* __restrict__ h0){
  __shared__ float xs[968];    // 8*121
  __shared__ float wsm[576];   // 8*8*9
  __shared__ float bs[8];
  int n = blockIdx.x, t = threadIdx.x;
  int isbf = flags[1];
  if (isbf){
    const ushort4* xp = (const ushort4*)((const u16*)xraw + (size_t)n*968);
    if (t < 242){ ushort4 u = xp[t]; xs[4*t]=bu2f(u.x); xs[4*t+1]=bu2f(u.y); xs[4*t+2]=bu2f(u.z); xs[4*t+3]=bu2f(u.w); }
  } else {
    const float4* xp = (const float4*)((const float*)xraw + (size_t)n*968);
    if (t < 242){ float4 u = xp[t]; xs[4*t]=u.x; xs[4*t+1]=u.y; xs[4*t+2]=u.z; xs[4*t+3]=u.w; }
  }
  if (t < 144){ float4 u = ((const float4*)cw)[t]; wsm[4*t]=u.x; wsm[4*t+1]=u.y; wsm[4*t+2]=u.z; wsm[4*t+3]=u.w; }
  if (t < 8) bs[t] = cb[t];
  __syncthreads();
  u16* outr = h0 + (size_t)n*704;
  if (t < 216){
    int co = t & 7;
    int rowid = t >> 3;        // 0..26
    int oi = rowid / 3;        // 0..8
    int og = rowid - oi*3;     // 0..2
    float wreg[72];
    #pragma unroll
    for (int q = 0; q < 72; q++) wreg[q] = wsm[co*72 + q];
    float a0 = bs[co], a1 = a0, a2 = a0;
    #pragma unroll
    for (int ci = 0; ci < 8; ci++){
      #pragma unroll
      for (int ki = 0; ki < 3; ki++){
        const float* xb = xs + ci*121 + (oi+ki)*11 + og*3;
        float x0=xb[0], x1=xb[1], x2=xb[2], x3=xb[3], x4=xb[4];
        float w0=wreg[ci*9+ki*3+0], w1=wreg[ci*9+ki*3+1], w2=wreg[ci*9+ki*3+2];
        a0 += x0*w0 + x1*w1 + x2*w2;
        a1 += x1*w0 + x2*w1 + x3*w2;
        a2 += x2*w0 + x3*w1 + x4*w2;
      }
    }
    int colbase = co*81 + oi*9 + og*3;
    outr[colbase+0] = f2bu(fmaxf(a0, 0.f));
    outr[colbase+1] = f2bu(fmaxf(a1, 0.f));
    outr[colbase+2] = f2bu(fmaxf(a2, 0.f));
  } else if (t < 220){
    int jj = t - 216;
    float v = isbf ? bu2f(((const u16*)bdraw)[(size_t)n*4 + jj]) : ((const float*)bdraw)[(size_t)n*4 + jj];
    outr[648 + jj] = f2bu(fmaxf(v, 0.f));
  } else {
    for (int c = 652 + (t - 220); c < 704; c += 36) outr[c] = 0;
  }
}

// ---------- degree ----------
__global__ void deg_kernel(const int* __restrict__ dst, int* __restrict__ degI, int E){
  int e = blockIdx.x*256 + threadIdx.x;
  if (e < E) atomicAdd(&degI[dst[e]], 1);
}
__global__ void invdeg_kernel(const int* __restrict__ degI, float* __restrict__ inv, int n){
  int i = blockIdx.x*256 + threadIdx.x;
  if (i < n){ int d = degI[i]; inv[i] = 1.0f / (float)(d > 1 ? d : 1); }
}

// ---------- exclusive scan of degI -> rowptr (single block, 1024 thr, 8 elem/thr) ----------
__global__ __launch_bounds__(1024) void scan_kernel(const int* __restrict__ degI,
                                                    int* __restrict__ rowptr,
                                                    int* __restrict__ cursor, int n){
  __shared__ int warp_sums[16];
  __shared__ int carry;
  int t = threadIdx.x;
  if (t == 0) carry = 0;
  __syncthreads();
  for (int base = 0; base < n; base += 8192){
    int i0 = base + t*8;
    int v[8]; int s = 0;
    #pragma unroll
    for (int q = 0; q < 8; q++){ int idx = i0+q; v[q] = (idx < n) ? degI[idx] : 0; s += v[q]; }
    int ts = s;
    #pragma unroll
    for (int off = 1; off < 64; off <<= 1){ int u = __shfl_up(ts, off); if ((t & 63) >= off) ts += u; }
    if ((t & 63) == 63) warp_sums[t >> 6] = ts;
    __syncthreads();
    if (t < 16){
      int wsv = warp_sums[t];
      #pragma unroll
      for (int off = 1; off < 16; off <<= 1){ int u = __shfl_up(wsv, off); if (t >= off) wsv += u; }
      warp_sums[t] = wsv;
    }
    __syncthreads();
    int blk = (t >= 64) ? warp_sums[(t >> 6) - 1] : 0;
    int excl = carry + blk + ts - s;
    #pragma unroll
    for (int q = 0; q < 8; q++){
      int idx = i0+q;
      if (idx < n){ rowptr[idx] = excl; cursor[idx] = excl; }
      excl += v[q];
    }
    int total = warp_sums[15];
    __syncthreads();
    if (t == 0) carry += total;
    __syncthreads();
  }
  if (t == 0) rowptr[n] = carry;
}

// ---------- bucket fill: ebuc[cursor[dst]++] = src ----------
__global__ void bucket_kernel(const int* __restrict__ esrc, const int* __restrict__ edst,
                              int* __restrict__ cursor, int* __restrict__ ebuc, int E){
  int e = blockIdx.x*256 + threadIdx.x;
  if (e < E){ int pos = atomicAdd(&cursor[edst[e]], 1); ebuc[pos] = esrc[e]; }
}

// ---------- gather-aggregate (bf16): out[n] = addbase[n] + scale[n]*sum src[nbr] ----------
// wave per node; lanes 0..31 = even edges, 32..63 = odd edges; 8 cols (16B) per lane.
__global__ __launch_bounds__(256) void gather_agg_kernel(
    const u16* __restrict__ src_feat, int s_stride,
    const u16* __restrict__ addbase, int a_stride,
    const float* __restrict__ scale, u16* __restrict__ outp,
    const int* __restrict__ rowptr, const int* __restrict__ ebuc){
  int wid = threadIdx.x >> 6, lane = threadIdx.x & 63;
  int n = blockIdx.x*4 + wid;
  if (n >= NN) return;
  int half = lane >> 5;
  int sub  = lane & 31;
  int c0 = sub * 8;
  int beg = rowptr[n], end = rowptr[n+1];
  float acc[8] = {0.f,0.f,0.f,0.f,0.f,0.f,0.f,0.f};
  int j = beg + half;
  for (; j + 2 < end; j += 4){
    int s0 = ebuc[j], s1 = ebuc[j+2];
    uint4 u0 = *(const uint4*)(src_feat + (size_t)s0*s_stride + c0);
    uint4 u1 = *(const uint4*)(src_feat + (size_t)s1*s_stride + c0);
    acc[0] += lo16f(u0.x); acc[1] += hi16f(u0.x);
    acc[2] += lo16f(u0.y); acc[3] += hi16f(u0.y);
    acc[4] += lo16f(u0.z); acc[5] += hi16f(u0.z);
    acc[6] += lo16f(u0.w); acc[7] += hi16f(u0.w);
    acc[0] += lo16f(u1.x); acc[1] += hi16f(u1.x);
    acc[2] += lo16f(u1.y); acc[3] += hi16f(u1.y);
    acc[4] += lo16f(u1.z); acc[5] += hi16f(u1.z);
    acc[6] += lo16f(u1.w); acc[7] += hi16f(u1.w);
  }
  for (; j < end; j += 2){
    int s0 = ebuc[j];
    uint4 u0 = *(const uint4*)(src_feat + (size_t)s0*s_stride + c0);
    acc[0] += lo16f(u0.x); acc[1] += hi16f(u0.x);
    acc[2] += lo16f(u0.y); acc[3] += hi16f(u0.y);
    acc[4] += lo16f(u0.z); acc[5] += hi16f(u0.z);
    acc[6] += lo16f(u0.w); acc[7] += hi16f(u0.w);
  }
  #pragma unroll
  for (int q = 0; q < 8; q++) acc[q] += __shfl_xor(acc[q], 32);
  if (half == 0){
    float sc = scale ? scale[n] : 1.f;
    #pragma unroll
    for (int q = 0; q < 8; q++) acc[q] *= sc;
    if (addbase){
      uint4 b = *(const uint4*)(addbase + (size_t)n*a_stride + c0);
      acc[0] += lo16f(b.x); acc[1] += hi16f(b.x);
      acc[2] += lo16f(b.y); acc[3] += hi16f(b.y);
      acc[4] += lo16f(b.z); acc[5] += hi16f(b.z);
      acc[6] += lo16f(b.w); acc[7] += hi16f(b.w);
    }
    uint4 o;
    o.x = (unsigned)f2bu(acc[0]) | ((unsigned)f2bu(acc[1]) << 16);
    o.y = (unsigned)f2bu(acc[2]) | ((unsigned)f2bu(acc[3]) << 16);
    o.z = (unsigned)f2bu(acc[4]) | ((unsigned)f2bu(acc[5]) << 16);
    o.w = (unsigned)f2bu(acc[6]) | ((unsigned)f2bu(acc[7]) << 16);
    *(uint4*)(outp + (size_t)n*256 + c0) = o;
  }
}

// ---------- MFMA bf16 GEMM: out = (A1 @ W1^T) + (A2 @ W2^T) + bias ----------
// A bf16 [M][lda], W bf16 [Nout][K] row-major, K % 64 == 0. Tile 128x128, BK=64, 4 waves 2x2.
__global__ __launch_bounds__(256) void gemm_mfma_kernel(
    const u16* __restrict__ A1, int lda1, const u16* __restrict__ W1, int K1,
    const u16* __restrict__ A2, int lda2, const u16* __restrict__ W2, int K2,
    const float* __restrict__ bias, int ldc,
    u16* __restrict__ out_bf,
    void* __restrict__ out_emb,
    u16* __restrict__ out_relu_bf,
    const int* __restrict__ flags, int M){
  __shared__ u16 Asm[128][72];   // stride 36 words: rows alias banks 2-way (free)
  __shared__ u16 Wsm[128][72];
  int t = threadIdx.x;
  int wave = t >> 6, lane = t & 63;
  int wr = wave >> 1, wc = wave & 1;
  int m0 = blockIdx.x << 7;
  int o0 = blockIdx.y << 7;
  int lrow = t >> 1;            // staging row 0..127
  int lk8  = (t & 1) << 3;      // staging k offset 0/8 (+16/+32/+48 more loads)
  int fr = lane & 15;
  int fkb = (lane >> 4) << 3;   // 0,8,16,24
  f32x4 acc[4][4] = {};

  for (int pass = 0; pass < 2; ++pass){
    const u16* A; const u16* W; int K, lda;
    if (pass == 0){ A = A1; W = W1; K = K1; lda = lda1; }
    else { if (!A2) break; A = A2; W = W2; K = K2; lda = lda2; }
    for (int k0 = 0; k0 < K; k0 += 64){
      int gm = m0 + lrow;
      int4 av0 = make_int4(0,0,0,0), av1 = av0, av2 = av0, av3 = av0;
      if (gm < M){
        const int4* ap = (const int4*)(A + (size_t)gm*lda + k0 + lk8);
        av0 = ap[0]; av1 = ap[2]; av2 = ap[4]; av3 = ap[6];
      }
      const int4* wp = (const int4*)(W + (size_t)(o0 + lrow)*K + k0 + lk8);
      int4 wv0 = wp[0], wv1 = wp[2], wv2 = wp[4], wv3 = wp[6];
      *(int4*)&Asm[lrow][lk8]      = av0;
      *(int4*)&Asm[lrow][lk8+16]   = av1;
      *(int4*)&Asm[lrow][lk8+32]   = av2;
      *(int4*)&Asm[lrow][lk8+48]   = av3;
      *(int4*)&Wsm[lrow][lk8]      = wv0;
      *(int4*)&Wsm[lrow][lk8+16]   = wv1;
      *(int4*)&Wsm[lrow][lk8+32]   = wv2;
      *(int4*)&Wsm[lrow][lk8+48]   = wv3;
      __syncthreads();
      #pragma unroll
      for (int kk = 0; kk < 2; kk++){
        int fk = kk*32 + fkb;
        bf16x8 af[4], wf[4];
        #pragma unroll
        for (int i = 0; i < 4; i++) af[i] = *(const bf16x8*)&Asm[wr*64 + i*16 + fr][fk];
        #pragma unroll
        for (int jj = 0; jj < 4; jj++) wf[jj] = *(const bf16x8*)&Wsm[wc*64 + jj*16 + fr][fk];
        #pragma unroll
        for (int i = 0; i < 4; i++)
          #pragma unroll
          for (int jj = 0; jj < 4; jj++)
            acc[i][jj] = __builtin_amdgcn_mfma_f32_16x16x32_bf16(af[i], wf[jj], acc[i][jj], 0, 0, 0);
      }
      __syncthreads();
    }
  }
  int isbf = flags[1];
  int fg = lane >> 4;
  #pragma unroll
  for (int i = 0; i < 4; i++){
    int rbase = m0 + wr*64 + i*16 + fg*4;
    #pragma unroll
    for (int jj = 0; jj < 4; jj++){
      int col = o0 + wc*64 + jj*16 + fr;
      float bv = bias[col];
      #pragma unroll
      for (int r = 0; r < 4; r++){
        int row = rbase + r;
        if (row < M){
          float v = acc[i][jj][r] + bv;
          size_t off = (size_t)row*ldc + col;
          if (out_bf)   out_bf[off] = f2bu(v);
          if (out_emb){
            if (isbf) ((u16*)out_emb)[off] = f2bu(v);
            else      ((float*)out_emb)[off] = v;
          }
          if (out_relu_bf) out_relu_bf[off] = f2bu(fmaxf(v, 0.f));
        }
      }
    }
  }
}

// ---------- relu + layernorm (bf16 in/out) ----------
__global__ __launch_bounds__(256) void relu_ln_kernel(
    const u16* __restrict__ inb, u16* __restrict__ outb,
    const float* __restrict__ g, const float* __restrict__ b){
  __shared__ float rs[4], rs2[4];
  int n = blockIdx.x, t = threadIdx.x;
  float v = fmaxf(bu2f(inb[(size_t)n*256 + t]), 0.f);
  float s = v, s2 = v*v;
  #pragma unroll
  for (int off = 1; off < 64; off <<= 1){ s += __shfl_xor(s, off); s2 += __shfl_xor(s2, off); }
  if ((t & 63) == 0){ rs[t>>6] = s; rs2[t>>6] = s2; }
  __syncthreads();
  float S  = rs[0]+rs[1]+rs[2]+rs[3];
  float S2 = rs2[0]+rs2[1]+rs2[2]+rs2[3];
  float mu  = S * (1.f/256.f);
  float var = S2 * (1.f/256.f) - mu*mu;
  float inv = rsqrtf(var + 1e-5f);
  outb[(size_t)n*256 + t] = f2bu((v - mu) * inv * g[t] + b[t]);
}

// ---------- head: z2 = z1 @ mp2^T + b2; log_softmax ----------
__global__ __launch_bounds__(256) void head_kernel(
    const u16* __restrict__ z1, const float* __restrict__ w2, const float* __restrict__ b2,
    void* __restrict__ outbase, size_t out_off, const int* __restrict__ flags, int M){
  __shared__ float wsm[1280];
  __shared__ float bs[5];
  int t = threadIdx.x;
  for (int i = t; i < 320; i += 256){
    float4 u = ((const float4*)w2)[i];
    wsm[4*i]=u.x; wsm[4*i+1]=u.y; wsm[4*i+2]=u.z; wsm[4*i+3]=u.w;
  }
  if (t < 5) bs[t] = b2[t];
  __syncthreads();
  int n = blockIdx.x*256 + t;
  if (n >= M) return;
  const u16* zp = z1 + (size_t)n*256;
  float acc[5];
  #pragma unroll
  for (int o = 0; o < 5; o++) acc[o] = bs[o];
  for (int k = 0; k < 256; k += 4){
    ushort4 zu = *(const ushort4*)(zp + k);
    float z0 = bu2f(zu.x), z1f = bu2f(zu.y), z2 = bu2f(zu.z), z3 = bu2f(zu.w);
    #pragma unroll
    for (int o = 0; o < 5; o++){
      const float* w = wsm + o*256 + k;
      acc[o] += z0*w[0] + z1f*w[1] + z2*w[2] + z3*w[3];
    }
  }
  float mx = acc[0];
  #pragma unroll
  for (int o = 1; o < 5; o++) mx = fmaxf(mx, acc[o]);
  float se = 0.f;
  #pragma unroll
  for (int o = 0; o < 5; o++) se += expf(acc[o] - mx);
  float lse = mx + logf(se);
  int isbf = flags[1];
  if (isbf){
    u16* op = (u16*)outbase + out_off + (size_t)n*5;
    #pragma unroll
    for (int o = 0; o < 5; o++) op[o] = f2bu(acc[o] - lse);
  } else {
    float* op = (float*)outbase + out_off + (size_t)n*5;
    #pragma unroll
    for (int o = 0; o < 5; o++) op[o] = acc[o] - lse;
  }
}

extern "C" void kernel_launch(void* const* d_in, const int* in_sizes, int n_in,
                              void* d_out, int out_size, void* d_ws, size_t ws_size,
                              hipStream_t stream){
  (void)in_sizes; (void)n_in; (void)out_size; (void)ws_size;
  const void* x    = d_in[0];
  const void* bd   = d_in[1];
  const void* eraw = d_in[2];

  char* ws = (char*)d_ws;
  const size_t OFF_H0 = 0;                                    // bf16 [NN][704]
  const size_t OFF_A  = OFF_H0 + (size_t)NN*704*2;            // bf16 [NN][256]
  const size_t OFF_B  = OFF_A  + (size_t)NN*256*2;            // bf16 [NN][256]  (bufAB low half)
  const size_t OFF_C  = OFF_B  + (size_t)NN*256*2;            // bf16 [NN][256]  (bufAB high half)
  const size_t OFF_DEG= OFF_C  + (size_t)NN*256*2;
  const size_t OFF_INV= OFF_DEG + (size_t)NN*4;
  const size_t OFF_EDG= OFF_INV + (size_t)NN*4;
  const size_t OFF_RP = OFF_EDG + (size_t)2*EE*4;
  const size_t OFF_CUR= OFF_RP  + (size_t)(NN+16)*4;
  const size_t OFF_EBU= OFF_CUR + (size_t)NN*4;
  const size_t OFF_FLG= OFF_EBU + (size_t)EE*4;
  const size_t OFF_PRM= OFF_FLG + 256;

  u16*   h0   = (u16*)(ws + OFF_H0);
  u16*   bufA = (u16*)(ws + OFF_A);
  u16*   bufB = (u16*)(ws + OFF_B);
  u16*   bufC = (u16*)(ws + OFF_C);
  u16*   bufAB= (u16*)(ws + OFF_B);   // [NN][512], aliases bufB+bufC (dead when reused)
  int*   degI = (int*)(ws + OFF_DEG);
  float* invd = (float*)(ws + OFF_INV);
  int*   edg  = (int*)(ws + OFF_EDG);
  int*   rowp = (int*)(ws + OFF_RP);
  int*   curs = (int*)(ws + OFF_CUR);
  int*   ebuc = (int*)(ws + OFF_EBU);
  int*   flg  = (int*)(ws + OFF_FLG);
  char*  prm  = ws + OFF_PRM;
  const int* esrc = edg;
  const int* edst = edg + EE;

  // canon entries: {rows, srcK, dstK (pad to mult of 64 for GEMM K), tobf}
  static const int crows[15] = {1,1,256,1,256,1,1,1,1,1,1,1,1,1,1};
  static const int csk[15]   = {576,8,652,256,652,256,196608,768,196608,512,512,65536,256,1280,5};
  static const int cdk[15]   = {576,8,704,256,704,256,196608,768,196608,512,512,65536,256,1280,5};
  static const int ctobf[15] = {0,0,1,0,1,0,1,0,1,0,0,1,0,0,0};
  CanonTab tab;
  size_t po = 0;
  void* dsts[15];
  for (int i = 0; i < 15; i++){
    tab.src[i] = d_in[3+i];
    tab.rows[i] = crows[i]; tab.sk[i] = csk[i]; tab.dk[i] = cdk[i]; tab.tobf[i] = ctobf[i];
    dsts[i] = prm + po;
    tab.dst[i] = dsts[i];
    size_t bytes = (size_t)crows[i]*cdk[i] * (ctobf[i] ? 2 : 4);
    po += (bytes + 63) & ~(size_t)63;
  }
  // fuse layer-0 weights/biases into contiguous [512][704] / [512]:
  // entry 4 (lin_self_w) -> rows 0..255 of c_l2w; entry 2 (lin_w) -> rows 256..511
  // entry 5 (lin_self_b) -> c_l2b[0..255];        entry 3 (lin_b) -> c_l2b[256..511]
  u16*   c_l2w = (u16*)dsts[4];
  float* c_l2b = (float*)(prm + po);  po += 512*4;
  tab.dst[2] = c_l2w + (size_t)256*704;
  tab.dst[3] = c_l2b + 256;
  tab.dst[5] = c_l2b;
  // NOTE: dsts[4] region must hold 512*704 bf16; entry4 allotted 256*704*2 B and entry5/3/2
  // regions are re-pointed, so reserve the extra explicitly:
  po += (size_t)256*704*2;

  const float* c_cw  = (const float*)dsts[0];
  const float* c_cb  = (const float*)dsts[1];
  const u16*   c_slw = (const u16*)dsts[6];
  const float* c_slb = (const float*)dsts[7];
  const u16*   c_srw = (const u16*)dsts[8];
  const float* c_lng = (const float*)dsts[9];
  const float* c_lnb = (const float*)dsts[10];
  const u16*   c_m1w = (const u16*)dsts[11];
  const float* c_m1b = (const float*)dsts[12];
  const float* c_m2w = (const float*)dsts[13];
  const float* c_m2b = (const float*)dsts[14];

  // entry 4 writes rows 0..255 in place; but rows 256..511 (entry 2's dst) must not
  // collide with entries 5..14 original slots. Entry 2's original slot is unused now;
  // the re-pointed dst for entry 2 lands inside dsts[4]+256*704 .. which overlaps
  // dsts[5..] ranges. Fix: place the fused W at fresh space at the end instead.
  {
    u16* fresh_w = (u16*)(prm + po);           // [512][704] bf16
    po += (size_t)512*704*2;
    float* fresh_b = (float*)(prm + po);       // [512] f32
    po += 512*4 + 64;
    tab.dst[4] = fresh_w;
    tab.dst[2] = fresh_w + (size_t)256*704;
    tab.dst[5] = fresh_b;
    tab.dst[3] = fresh_b + 256;
    c_l2w = fresh_w;
    c_l2b = fresh_b;
  }

  hipMemsetAsync(degI, 0, (size_t)NN*4, stream);
  sniff_kernel<<<1, 256, 0, stream>>>((const int*)eraw, (const u16*)x, flg);
  {
    dim3 cgrid(96, 15);
    canon_params_kernel<<<cgrid, 256, 0, stream>>>(tab, flg);
  }
  convert_edges_kernel<<<(2*EE + 255)/256, 256, 0, stream>>>(eraw, edg, flg, 2*EE);
  conv_relu_kernel<<<NN, 256, 0, stream>>>(x, bd, c_cw, c_cb, flg, h0);
  deg_kernel<<<(EE + 255)/256, 256, 0, stream>>>(edst, degI, EE);
  invdeg_kernel<<<(NN + 255)/256, 256, 0, stream>>>(degI, invd, NN);
  scan_kernel<<<1, 1024, 0, stream>>>(degI, rowp, curs, NN);
  bucket_kernel<<<(EE + 255)/256, 256, 0, stream>>>(esrc, edst, curs, ebuc, EE);

  dim3 ggrid((NN + 127)/128, 2);
  dim3 ggrid0((NN + 127)/128, 4);
  const int agrid = (NN + 3)/4;
  // layer 0 (fused): bufAB[:, 0:256] = self_x, bufAB[:, 256:512] = neigh
  gemm_mfma_kernel<<<ggrid0, 256, 0, stream>>>(h0, 704, c_l2w, 704,
      nullptr, 0, nullptr, 0, c_l2b, 512, bufAB, nullptr, nullptr, flg, NN);
  // bufA[n] = self[n] + sum_in neigh[src]
  gather_agg_kernel<<<agrid, 256, 0, stream>>>(bufAB + 256, 512, bufAB, 512,
      nullptr, bufA, rowp, ebuc);

  // SAGE layers: h in bufA; mean-agg (pre-scaled by invd) in bufC; gemm -> bufB
  for (int i = 0; i < 3; i++){
    gather_agg_kernel<<<agrid, 256, 0, stream>>>(bufA, 256, nullptr, 0,
        invd, bufC, rowp, ebuc);
    const u16*   L  = c_slw + (size_t)i*256*256;
    const float* Lb = c_slb + (size_t)i*256;
    const u16*   R  = c_srw + (size_t)i*256*256;
    if (i < 2){
      gemm_mfma_kernel<<<ggrid, 256, 0, stream>>>(bufC, 256, L, 256,
          bufA, 256, R, 256, Lb, 256, bufB, nullptr, nullptr, flg, NN);
      relu_ln_kernel<<<NN, 256, 0, stream>>>(bufB, bufA,
          c_lng + (size_t)i*256, c_lnb + (size_t)i*256);
    } else {
      gemm_mfma_kernel<<<ggrid, 256, 0, stream>>>(bufC, 256, L, 256,
          bufA, 256, R, 256, Lb, 256, nullptr, d_out, bufB, flg, NN);
    }
  }
  gemm_mfma_kernel<<<ggrid, 256, 0, stream>>>(bufB, 256, c_m1w, 256,
      nullptr, 0, nullptr, 0, c_m1b, 256, bufC, nullptr, nullptr, flg, NN);
  head_kernel<<<(NN + 255)/256, 256, 0, stream>>>(bufC, c_m2w, c_m2b,
      d_out, (size_t)NN*256, flg, NN);
}